// Round 1
// baseline (194.592 us; speedup 1.0000x reference)
//
#include <hip/hip_runtime.h>
#include <cmath>

#define NLOC 1940
#define NPRI 8732
#define BATCH 16
#define KOBJ 10

// prior index -> location index (matches _recon_indices)
__device__ __forceinline__ int loc_of_prior(int p) {
    if (p < 5776) return p >> 2;                       // fm 38, bpl 4
    if (p < 7942) return 1444 + (p - 5776) / 6;        // fm 19, bpl 6
    if (p < 8542) return 1805 + (p - 7942) / 6;        // fm 10, bpl 6
    if (p < 8692) return 1905 + (p - 8542) / 6;        // fm 5,  bpl 6
    if (p < 8728) return 1930 + ((p - 8692) >> 2);     // fm 3,  bpl 4
    return 1939 + ((p - 8728) >> 2);                   // fm 1,  bpl 4
}

// ---------------------------------------------------------------------------
// Kernel 1: per-batch top-10 priors by depth (stable: value desc, index asc),
// gather z_what (all 10), and emit compacted present-object STN params.
// ---------------------------------------------------------------------------
__global__ __launch_bounds__(256) void topk_kernel(
    const float* __restrict__ z_what, const float* __restrict__ z_where,
    const int* __restrict__ z_present, const float* __restrict__ z_depth,
    float* __restrict__ gathered, float* __restrict__ paramsF, int* __restrict__ paramsI)
{
    const int b = blockIdx.x, tid = threadIdx.x;
    __shared__ float zd[NPRI];
    __shared__ float rv[256];
    __shared__ int   ri[256];
    __shared__ int   ord[KOBJ];
    __shared__ int   locs[KOBJ];

    for (int p = tid; p < NPRI; p += 256) zd[p] = z_depth[b * NLOC + loc_of_prior(p)];
    __syncthreads();

    for (int k = 0; k < KOBJ; ++k) {
        float bv = -INFINITY; int bi = NPRI;
        for (int p = tid; p < NPRI; p += 256) {
            float v = zd[p];
            if (v > bv) { bv = v; bi = p; }   // strict > keeps smallest index in stride set
        }
        rv[tid] = bv; ri[tid] = bi;
        __syncthreads();
        for (int s = 128; s > 0; s >>= 1) {
            if (tid < s) {
                float v2 = rv[tid + s]; int i2 = ri[tid + s];
                if (v2 > rv[tid] || (v2 == rv[tid] && i2 < ri[tid])) { rv[tid] = v2; ri[tid] = i2; }
            }
            __syncthreads();
        }
        if (tid == 0) {
            int w = ri[0];
            ord[k] = w; locs[k] = loc_of_prior(w);
            zd[w] = -INFINITY;
        }
        __syncthreads();
    }

    // gather z_what for all 10 objects (decoded regardless of presence, like ref)
    for (int e = tid; e < KOBJ * 64; e += 256) {
        int k = e >> 6, c = e & 63;
        gathered[(b * KOBJ + k) * 64 + c] = z_what[(b * NLOC + locs[k]) * 64 + c];
    }

    if (tid == 0) {
        int cnt = 0;
        for (int k = 0; k < KOBJ; ++k) {
            int p = ord[k];
            if (z_present[b * NPRI + p] == 1) {
                const float* zw = z_where + (b * NPRI + p) * 4;
                float cx = zw[0], cy = zw[1], w_ = zw[2], h_ = zw[3];
                float* pf = paramsF + (b * KOBJ + cnt) * 4;
                pf[0] = __fadd_rn(w_, 1e-6f);                       // w + eps
                pf[1] = __fadd_rn(h_, 1e-6f);                       // h + eps
                pf[2] = __fsub_rn(__fmul_rn(2.0f, cx), 1.0f);       // 2cx-1
                pf[3] = __fsub_rn(__fmul_rn(2.0f, cy), 1.0f);       // 2cy-1
                paramsI[b * 12 + 2 + cnt] = b * KOBJ + k;           // decoded sample idx
                cnt++;
            }
        }
        paramsI[b * 12] = cnt;
    }
}

// ---------------------------------------------------------------------------
// Generic deconv2x2 layer: out[f= o*4+a*2+b][p] = bias[o] + sum_c in[c][p]*W[c*4O+f]
// in_s: LDS, natural [C][H][W]. MODE 0: relu -> LDS natural [O][2H][2W]
// MODE 1: relu -> global flat [F][hw] (coalesced). MODE 2: sigmoid -> global natural 64x64.
// ---------------------------------------------------------------------------
template<int C, int O, int H, int W, int TS, int TO, int MODE>
__device__ __forceinline__ void layer_compute(
    const float* __restrict__ Wt, const float* __restrict__ Bs,
    const float* in_s, float* out_s, float* __restrict__ out_g)
{
    constexpr int hw = H * W;
    constexpr int F  = 4 * O;
    constexpr int CH = hw / TS;
    constexpr int FG = F / TO;
    const int tid = threadIdx.x;
    for (int task = tid; task < CH * FG; task += 256) {
        const int ch = task % CH;
        const int fg = task / CH;
        const int f0 = fg * TO;
        const int p0 = ch * TS;
        float acc[TO][TS];
        #pragma unroll
        for (int j = 0; j < TO; ++j) {
            float bv = Bs[(f0 + j) >> 2];
            #pragma unroll
            for (int s = 0; s < TS; ++s) acc[j][s] = bv;
        }
        for (int c = 0; c < C; ++c) {
            float xin[TS];
            if constexpr (TS == 1) {
                xin[0] = in_s[c];
            } else {
                #pragma unroll
                for (int s4 = 0; s4 < TS; s4 += 4) {
                    float4 v = *reinterpret_cast<const float4*>(in_s + c * hw + p0 + s4);
                    xin[s4 + 0] = v.x; xin[s4 + 1] = v.y; xin[s4 + 2] = v.z; xin[s4 + 3] = v.w;
                }
            }
            float wv[TO];
            if constexpr (TO % 4 == 0) {
                #pragma unroll
                for (int j4 = 0; j4 < TO; j4 += 4) {
                    float4 v = *reinterpret_cast<const float4*>(Wt + c * F + f0 + j4);
                    wv[j4 + 0] = v.x; wv[j4 + 1] = v.y; wv[j4 + 2] = v.z; wv[j4 + 3] = v.w;
                }
            } else {
                float2 v = *reinterpret_cast<const float2*>(Wt + c * F + f0);
                wv[0] = v.x; wv[1] = v.y;
            }
            #pragma unroll
            for (int j = 0; j < TO; ++j) {
                #pragma unroll
                for (int s = 0; s < TS; ++s)
                    acc[j][s] = fmaf(xin[s], wv[j], acc[j][s]);
            }
        }
        if constexpr (MODE == 1) {
            #pragma unroll
            for (int j = 0; j < TO; ++j) {
                #pragma unroll
                for (int s4 = 0; s4 < TS; s4 += 4) {
                    float4 v;
                    v.x = fmaxf(acc[j][s4 + 0], 0.0f);
                    v.y = fmaxf(acc[j][s4 + 1], 0.0f);
                    v.z = fmaxf(acc[j][s4 + 2], 0.0f);
                    v.w = fmaxf(acc[j][s4 + 3], 0.0f);
                    *reinterpret_cast<float4*>(out_g + (f0 + j) * hw + p0 + s4) = v;
                }
            }
        } else {
            #pragma unroll
            for (int s = 0; s < TS; ++s) {
                const int p = p0 + s;
                const int h = p / W, w = p % W;
                #pragma unroll
                for (int j = 0; j < TO; j += 2) {
                    const int f = f0 + j;
                    const int o = f >> 2, a = (f >> 1) & 1;
                    float v0 = acc[j][s], v1 = acc[j + 1][s];
                    if constexpr (MODE == 0) {
                        v0 = fmaxf(v0, 0.0f); v1 = fmaxf(v1, 0.0f);
                        *reinterpret_cast<float2*>(out_s + (o * 2 * H + 2 * h + a) * 2 * W + 2 * w)
                            = make_float2(v0, v1);
                    } else {
                        v0 = 1.0f / (1.0f + expf(-v0));
                        v1 = 1.0f / (1.0f + expf(-v1));
                        *reinterpret_cast<float2*>(out_g + (o * 64 + 2 * h + a) * 64 + 2 * w)
                            = make_float2(v0, v1);
                    }
                }
            }
        }
    }
}

// Layers 0-4, one block per decoded sample, activations ping-pong in LDS.
__global__ __launch_bounds__(256) void dec_kernel_a(
    const float* __restrict__ gathered,
    const float* __restrict__ W0, const float* __restrict__ b0,
    const float* __restrict__ W1, const float* __restrict__ b1,
    const float* __restrict__ W2, const float* __restrict__ b2,
    const float* __restrict__ W3, const float* __restrict__ b3,
    const float* __restrict__ W4, const float* __restrict__ b4,
    float* __restrict__ l4flat)
{
    __shared__ float A[8192];
    __shared__ float B[4096];
    const int samp = blockIdx.x;
    const int tid = threadIdx.x;
    if (tid < 64) A[tid] = gathered[samp * 64 + tid];
    __syncthreads();
    layer_compute<64, 256, 1, 1, 1, 4, 0>(W0, b0, A, B, nullptr);    // A(64)   -> B(1024)
    __syncthreads();
    layer_compute<256, 128, 2, 2, 4, 2, 0>(W1, b1, B, A, nullptr);   // B(1024) -> A(2048)
    __syncthreads();
    layer_compute<128, 64, 4, 4, 4, 4, 0>(W2, b2, A, B, nullptr);    // A(2048) -> B(4096)
    __syncthreads();
    layer_compute<64, 32, 8, 8, 4, 8, 0>(W3, b3, B, A, nullptr);     // B(4096) -> A(8192)
    __syncthreads();
    layer_compute<32, 16, 16, 16, 8, 8, 1>(W4, b4, A, nullptr, l4flat + samp * 16384);
}

// Layer 5: flat global -> permuted LDS natural [16][32][32] -> sigmoid -> decoded natural [3][64][64]
__global__ __launch_bounds__(256) void dec_kernel_b(
    const float* __restrict__ l4flat, const float* __restrict__ W5, const float* __restrict__ b5,
    float* __restrict__ decoded)
{
    __shared__ float NAT[16384];
    const int samp = blockIdx.x;
    const int tid = threadIdx.x;
    const float* in_g = l4flat + samp * 16384;
    for (int g0 = tid * 4; g0 < 16384; g0 += 1024) {
        float4 v = *reinterpret_cast<const float4*>(in_g + g0);
        float tmp[4] = {v.x, v.y, v.z, v.w};
        #pragma unroll
        for (int i = 0; i < 4; ++i) {
            int g = g0 + i;
            int f = g >> 8, p = g & 255;
            int o = f >> 2, a = (f >> 1) & 1, bb = f & 1;
            int h = p >> 4, w = p & 15;
            NAT[o * 1024 + (2 * h + a) * 32 + 2 * w + bb] = tmp[i];
        }
    }
    __syncthreads();
    layer_compute<16, 3, 32, 32, 4, 12, 2>(W5, b5, NAT, nullptr, decoded + samp * 12288);
}

// ---------------------------------------------------------------------------
// Kernel 4: STN + first-nonzero composite. Geometry chain bitwise-matches ref
// (IEEE single ops via __f*_rn, reference op order). Coverage test is exact:
// sample != 0  <=>  ix in (-1,64) and iy in (-1,64)   (decoded > 0 strictly).
// ---------------------------------------------------------------------------
__global__ __launch_bounds__(256) void stn_kernel(
    const float* __restrict__ decoded, const float* __restrict__ paramsF,
    const int* __restrict__ paramsI, float* __restrict__ out)
{
    const int b = blockIdx.y;
    __shared__ float sp[KOBJ][4];
    __shared__ int ssamp[KOBJ];
    __shared__ int scnt;
    if (threadIdx.x == 0) scnt = paramsI[b * 12];
    if (threadIdx.x < KOBJ) {
        #pragma unroll
        for (int c = 0; c < 4; ++c) sp[threadIdx.x][c] = paramsF[(b * KOBJ + threadIdx.x) * 4 + c];
        ssamp[threadIdx.x] = paramsI[b * 12 + 2 + threadIdx.x];
    }
    __syncthreads();
    const int pix = blockIdx.x * 256 + threadIdx.x;
    if (pix >= 90000) return;
    const int y = pix / 300;
    const int x = pix - y * 300;
    const float xo = __fsub_rn(__fdiv_rn(__fadd_rn(__fmul_rn(2.0f, (float)x), 1.0f), 300.0f), 1.0f);
    const float yo = __fsub_rn(__fdiv_rn(__fadd_rn(__fmul_rn(2.0f, (float)y), 1.0f), 300.0f), 1.0f);

    float o0 = 0.0f, o1 = 0.0f, o2 = 0.0f;
    bool d0 = false, d1 = false, d2 = false;
    const int cnt = scnt;
    for (int k = 0; k < cnt; ++k) {
        const float u = __fdiv_rn(__fsub_rn(xo, sp[k][2]), sp[k][0]);
        const float v = __fdiv_rn(__fsub_rn(yo, sp[k][3]), sp[k][1]);
        const float ix = __fmul_rn(__fsub_rn(__fmul_rn(__fadd_rn(u, 1.0f), 64.0f), 1.0f), 0.5f);
        const float iy = __fmul_rn(__fsub_rn(__fmul_rn(__fadd_rn(v, 1.0f), 64.0f), 1.0f), 0.5f);
        if (!(ix > -1.0f && ix < 64.0f && iy > -1.0f && iy < 64.0f)) continue;

        const float ix0f = floorf(ix), iy0f = floorf(iy);
        const float ix1f = __fadd_rn(ix0f, 1.0f), iy1f = __fadd_rn(iy0f, 1.0f);
        const float wx1 = __fsub_rn(ix, ix0f), wy1 = __fsub_rn(iy, iy0f);
        const float wx0 = __fsub_rn(1.0f, wx1), wy0 = __fsub_rn(1.0f, wy1);
        const bool vx0 = (ix0f >= 0.0f) && (ix0f < 64.0f);
        const bool vx1 = (ix1f >= 0.0f) && (ix1f < 64.0f);
        const bool vy0 = (iy0f >= 0.0f) && (iy0f < 64.0f);
        const bool vy1 = (iy1f >= 0.0f) && (iy1f < 64.0f);
        const int x0 = (int)fminf(fmaxf(ix0f, 0.0f), 63.0f);
        const int x1 = (int)fminf(fmaxf(ix1f, 0.0f), 63.0f);
        const int y0i = (int)fminf(fmaxf(iy0f, 0.0f), 63.0f);
        const int y1i = (int)fminf(fmaxf(iy1f, 0.0f), 63.0f);
        const int r00 = y0i * 64 + x0, r01 = y0i * 64 + x1;
        const int r10 = y1i * 64 + x0, r11 = y1i * 64 + x1;
        const bool m00 = vy0 && vx0, m01 = vy0 && vx1, m10 = vy1 && vx0, m11 = vy1 && vx1;
        const float* img = decoded + ssamp[k] * 12288;

        auto sample_ch = [&](int o) -> float {
            const float* base = img + o * 4096;
            float g00 = m00 ? base[r00] : 0.0f;
            float g01 = m01 ? base[r01] : 0.0f;
            float g10 = m10 ? base[r10] : 0.0f;
            float g11 = m11 ? base[r11] : 0.0f;
            return g00 * wy0 * wx0 + g01 * wy0 * wx1 + g10 * wy1 * wx0 + g11 * wy1 * wx1;
        };
        if (!d0) { float val = sample_ch(0); if (val != 0.0f) { o0 = val; d0 = true; } }
        if (!d1) { float val = sample_ch(1); if (val != 0.0f) { o1 = val; d1 = true; } }
        if (!d2) { float val = sample_ch(2); if (val != 0.0f) { o2 = val; d2 = true; } }
        if (d0 && d1 && d2) break;
    }
    const int ob = b * 270000 + pix;
    out[ob] = o0;
    out[ob + 90000] = o1;
    out[ob + 180000] = o2;
}

extern "C" void kernel_launch(void* const* d_in, const int* in_sizes, int n_in,
                              void* d_out, int out_size, void* d_ws, size_t ws_size,
                              hipStream_t stream)
{
    const float* z_what    = (const float*)d_in[0];
    const float* z_where   = (const float*)d_in[1];
    const int*   z_present = (const int*)d_in[2];
    const float* z_depth   = (const float*)d_in[3];
    const float* W0 = (const float*)d_in[4];   const float* b0 = (const float*)d_in[5];
    const float* W1 = (const float*)d_in[6];   const float* b1 = (const float*)d_in[7];
    const float* W2 = (const float*)d_in[8];   const float* b2 = (const float*)d_in[9];
    const float* W3 = (const float*)d_in[10];  const float* b3 = (const float*)d_in[11];
    const float* W4 = (const float*)d_in[12];  const float* b4 = (const float*)d_in[13];
    const float* W5 = (const float*)d_in[14];  const float* b5 = (const float*)d_in[15];

    float* ws = (float*)d_ws;
    float* gathered = ws;                       // 160*64    = 10240 floats
    float* paramsF  = ws + 16384;               // 16*10*4   = 640 floats
    int*   paramsI  = (int*)(ws + 17408);       // 16*12     = 192 ints
    float* decoded  = ws + 32768;               // 160*12288 = 1,966,080 floats (~7.6 MB total)
    float* l4flat   = (float*)d_out;            // scratch: 160*16384 = 2.62M floats <= out_size
    float* outp     = (float*)d_out;            // final output overwrites scratch after use

    hipLaunchKernelGGL(topk_kernel, dim3(BATCH), dim3(256), 0, stream,
                       z_what, z_where, z_present, z_depth, gathered, paramsF, paramsI);
    hipLaunchKernelGGL(dec_kernel_a, dim3(BATCH * KOBJ), dim3(256), 0, stream,
                       gathered, W0, b0, W1, b1, W2, b2, W3, b3, W4, b4, l4flat);
    hipLaunchKernelGGL(dec_kernel_b, dim3(BATCH * KOBJ), dim3(256), 0, stream,
                       l4flat, W5, b5, decoded);
    hipLaunchKernelGGL(stn_kernel, dim3(352, BATCH), dim3(256), 0, stream,
                       decoded, paramsF, paramsI, outp);
}

// Round 3
// 194.326 us; speedup vs baseline: 1.0014x; 1.0014x over previous
//
#include <hip/hip_runtime.h>
#include <cmath>

#define NLOC 1940
#define NPRI 8732
#define BATCH 16
#define KOBJ 10

// prior index -> location index (matches _recon_indices)
__device__ __forceinline__ int loc_of_prior(int p) {
    if (p < 5776) return p >> 2;                       // fm 38, bpl 4
    if (p < 7942) return 1444 + (p - 5776) / 6;        // fm 19, bpl 6
    if (p < 8542) return 1805 + (p - 7942) / 6;        // fm 10, bpl 6
    if (p < 8692) return 1905 + (p - 8542) / 6;        // fm 5,  bpl 6
    if (p < 8728) return 1930 + ((p - 8692) >> 2);     // fm 3,  bpl 4
    return 1939 + ((p - 8728) >> 2);                   // fm 1,  bpl 4
}

// ---------------------------------------------------------------------------
// Kernel 1: per-batch top-10 priors by depth (stable: value desc, index asc),
// gather z_what (all 10), and emit compacted present-object STN params.
// ---------------------------------------------------------------------------
__global__ __launch_bounds__(256) void topk_kernel(
    const float* __restrict__ z_what, const float* __restrict__ z_where,
    const int* __restrict__ z_present, const float* __restrict__ z_depth,
    float* __restrict__ gathered, float* __restrict__ paramsF, int* __restrict__ paramsI)
{
    const int b = blockIdx.x, tid = threadIdx.x;
    __shared__ float zd[NPRI];
    __shared__ float rv[256];
    __shared__ int   ri[256];
    __shared__ int   ord[KOBJ];
    __shared__ int   locs[KOBJ];

    for (int p = tid; p < NPRI; p += 256) zd[p] = z_depth[b * NLOC + loc_of_prior(p)];
    __syncthreads();

    for (int k = 0; k < KOBJ; ++k) {
        float bv = -INFINITY; int bi = NPRI;
        for (int p = tid; p < NPRI; p += 256) {
            float v = zd[p];
            if (v > bv) { bv = v; bi = p; }   // strict > keeps smallest index in stride set
        }
        rv[tid] = bv; ri[tid] = bi;
        __syncthreads();
        for (int s = 128; s > 0; s >>= 1) {
            if (tid < s) {
                float v2 = rv[tid + s]; int i2 = ri[tid + s];
                if (v2 > rv[tid] || (v2 == rv[tid] && i2 < ri[tid])) { rv[tid] = v2; ri[tid] = i2; }
            }
            __syncthreads();
        }
        if (tid == 0) {
            int w = ri[0];
            ord[k] = w; locs[k] = loc_of_prior(w);
            zd[w] = -INFINITY;
        }
        __syncthreads();
    }

    for (int e = tid; e < KOBJ * 64; e += 256) {
        int k = e >> 6, c = e & 63;
        gathered[(b * KOBJ + k) * 64 + c] = z_what[(b * NLOC + locs[k]) * 64 + c];
    }

    if (tid == 0) {
        int cnt = 0;
        for (int k = 0; k < KOBJ; ++k) {
            int p = ord[k];
            if (z_present[b * NPRI + p] == 1) {
                const float* zw = z_where + (b * NPRI + p) * 4;
                float cx = zw[0], cy = zw[1], w_ = zw[2], h_ = zw[3];
                float* pf = paramsF + (b * KOBJ + cnt) * 4;
                pf[0] = __fadd_rn(w_, 1e-6f);
                pf[1] = __fadd_rn(h_, 1e-6f);
                pf[2] = __fsub_rn(__fmul_rn(2.0f, cx), 1.0f);
                pf[3] = __fsub_rn(__fmul_rn(2.0f, cy), 1.0f);
                paramsI[b * 12 + 2 + cnt] = b * KOBJ + k;
                cnt++;
            }
        }
        paramsI[b * 12] = cnt;
    }
}

// ---------------------------------------------------------------------------
// Fused decoder stage: in LDS natural [C][H][W] -> out.
// MODE 0: relu -> LDS natural [O][2H][2W] (scalar writes).
// MODE 2: sigmoid -> global channel-last [(ry+2h+a)*64 + rx+2w+b][3].
// f = o*4 + a*2 + b; 256 threads.
// ---------------------------------------------------------------------------
template<int C, int O, int H, int W, int TS, int TO, int MODE>
__device__ __forceinline__ void stage(
    const float* __restrict__ Wt, const float* __restrict__ Bs,
    const float* in_s, float* out_s, float* __restrict__ out_g, int ry, int rx)
{
    constexpr int hw = H * W;
    constexpr int F  = 4 * O;
    constexpr int CH = hw / TS;
    constexpr int FG = F / TO;
    const int tid = threadIdx.x;
    for (int task = tid; task < CH * FG; task += 256) {
        const int ch = task % CH;
        const int fg = task / CH;
        const int f0 = fg * TO;
        const int p0 = ch * TS;
        float acc[TO][TS];
        #pragma unroll
        for (int j = 0; j < TO; ++j) {
            float bv = Bs[(f0 + j) >> 2];
            #pragma unroll
            for (int s = 0; s < TS; ++s) acc[j][s] = bv;
        }
        for (int c = 0; c < C; ++c) {
            float xin[TS];
            if constexpr (TS == 1) {
                xin[0] = in_s[c];
            } else {
                #pragma unroll
                for (int s4 = 0; s4 < TS; s4 += 4) {
                    float4 v = *reinterpret_cast<const float4*>(in_s + c * hw + p0 + s4);
                    xin[s4 + 0] = v.x; xin[s4 + 1] = v.y; xin[s4 + 2] = v.z; xin[s4 + 3] = v.w;
                }
            }
            float wv[TO];
            if constexpr (TO == 1) {
                wv[0] = Wt[c * F + f0];
            } else if constexpr (TO == 2) {
                float2 v = *reinterpret_cast<const float2*>(Wt + c * F + f0);
                wv[0] = v.x; wv[1] = v.y;
            } else {
                #pragma unroll
                for (int j4 = 0; j4 < TO; j4 += 4) {
                    float4 v = *reinterpret_cast<const float4*>(Wt + c * F + f0 + j4);
                    wv[j4 + 0] = v.x; wv[j4 + 1] = v.y; wv[j4 + 2] = v.z; wv[j4 + 3] = v.w;
                }
            }
            #pragma unroll
            for (int j = 0; j < TO; ++j) {
                #pragma unroll
                for (int s = 0; s < TS; ++s)
                    acc[j][s] = fmaf(xin[s], wv[j], acc[j][s]);
            }
        }
        #pragma unroll
        for (int s = 0; s < TS; ++s) {
            const int p = p0 + s;
            const int h = p / W, w = p % W;
            #pragma unroll
            for (int j = 0; j < TO; ++j) {
                const int f = f0 + j;
                const int o = f >> 2, a = (f >> 1) & 1, bb = f & 1;
                float v = acc[j][s];
                if constexpr (MODE == 0) {
                    out_s[(o * 2 * H + 2 * h + a) * (2 * W) + 2 * w + bb] = fmaxf(v, 0.0f);
                } else {
                    v = 1.0f / (1.0f + expf(-v));
                    out_g[((ry + 2 * h + a) * 64 + (rx + 2 * w + bb)) * 3 + o] = v;
                }
            }
        }
    }
}

// All 6 layers fused; one block per (sample, layer-0 quadrant). Deconv2x2 has
// no spatial overlap, so quadrant (a0,b0) of layer-0 output evolves
// independently into final region [a0*32:+32, b0*32:+32].
// grid.y MUST be BATCH*KOBJ = 160 samples (round-2 bug: was BATCH).
__global__ __launch_bounds__(256) void dec_fused(
    const float* __restrict__ gathered,
    const float* __restrict__ W0, const float* __restrict__ b0,
    const float* __restrict__ W1, const float* __restrict__ b1,
    const float* __restrict__ W2, const float* __restrict__ b2,
    const float* __restrict__ W3, const float* __restrict__ b3,
    const float* __restrict__ W4, const float* __restrict__ b4,
    const float* __restrict__ W5, const float* __restrict__ b5,
    float* __restrict__ decoded)
{
    __shared__ __align__(16) float A[4096];
    __shared__ __align__(16) float B[2048];
    __shared__ float Z[64];
    const int q    = blockIdx.x;   // layer-0 output quadrant: a0 = q>>1, b0 = q&1
    const int samp = blockIdx.y;   // 0 .. BATCH*KOBJ-1
    const int tid  = threadIdx.x;
    if (tid < 64) Z[tid] = gathered[samp * 64 + tid];
    __syncthreads();
    // S0 (quadrant-restricted GEMV): x0[o] = relu(b0[o] + sum_c z[c]*W0[c,o,a0,b0])
    {
        float acc = b0[tid];
        for (int c = 0; c < 64; ++c)
            acc = fmaf(Z[c], W0[(c * 256 + tid) * 4 + q], acc);
        A[tid] = fmaxf(acc, 0.0f);
    }
    __syncthreads();
    stage<256, 128, 1, 1, 1, 2, 0>(W1, b1, A, B, nullptr, 0, 0);   // A(256)  -> B(512)
    __syncthreads();
    stage<128, 64, 2, 2, 4, 1, 0>(W2, b2, B, A, nullptr, 0, 0);    // B(512)  -> A(1024)
    __syncthreads();
    stage<64, 32, 4, 4, 4, 2, 0>(W3, b3, A, B, nullptr, 0, 0);     // A(1024) -> B(2048)
    __syncthreads();
    stage<32, 16, 8, 8, 4, 4, 0>(W4, b4, B, A, nullptr, 0, 0);     // B(2048) -> A(4096)
    __syncthreads();
    stage<16, 3, 16, 16, 4, 1, 2>(W5, b5, A, nullptr,
                                  decoded + samp * 12288, (q >> 1) * 32, (q & 1) * 32);
}

// ---------------------------------------------------------------------------
// STN + first-nonzero composite. Geometry chain bitwise-matches ref (IEEE
// single ops, reference op order). decoded is channel-last [4096 px][3] so a
// corner's 3 channels are one contiguous 12B load.
// ---------------------------------------------------------------------------
__global__ __launch_bounds__(256) void stn_kernel(
    const float* __restrict__ decoded, const float* __restrict__ paramsF,
    const int* __restrict__ paramsI, float* __restrict__ out)
{
    const int b = blockIdx.y;
    __shared__ float sp[KOBJ][4];
    __shared__ int ssamp[KOBJ];
    __shared__ int scnt;
    if (threadIdx.x == 0) scnt = paramsI[b * 12];
    if (threadIdx.x < KOBJ) {
        #pragma unroll
        for (int c = 0; c < 4; ++c) sp[threadIdx.x][c] = paramsF[(b * KOBJ + threadIdx.x) * 4 + c];
        ssamp[threadIdx.x] = paramsI[b * 12 + 2 + threadIdx.x];
    }
    __syncthreads();
    const int pix = blockIdx.x * 256 + threadIdx.x;
    if (pix >= 90000) return;
    const int y = pix / 300;
    const int x = pix - y * 300;
    const float xo = __fsub_rn(__fdiv_rn(__fadd_rn(__fmul_rn(2.0f, (float)x), 1.0f), 300.0f), 1.0f);
    const float yo = __fsub_rn(__fdiv_rn(__fadd_rn(__fmul_rn(2.0f, (float)y), 1.0f), 300.0f), 1.0f);

    float o0 = 0.0f, o1 = 0.0f, o2 = 0.0f;
    bool d0 = false, d1 = false, d2 = false;
    const int cnt = scnt;
    for (int k = 0; k < cnt; ++k) {
        const float u = __fdiv_rn(__fsub_rn(xo, sp[k][2]), sp[k][0]);
        const float v = __fdiv_rn(__fsub_rn(yo, sp[k][3]), sp[k][1]);
        const float ix = __fmul_rn(__fsub_rn(__fmul_rn(__fadd_rn(u, 1.0f), 64.0f), 1.0f), 0.5f);
        const float iy = __fmul_rn(__fsub_rn(__fmul_rn(__fadd_rn(v, 1.0f), 64.0f), 1.0f), 0.5f);
        if (!(ix > -1.0f && ix < 64.0f && iy > -1.0f && iy < 64.0f)) continue;

        const float ix0f = floorf(ix), iy0f = floorf(iy);
        const float ix1f = __fadd_rn(ix0f, 1.0f), iy1f = __fadd_rn(iy0f, 1.0f);
        const float wx1 = __fsub_rn(ix, ix0f), wy1 = __fsub_rn(iy, iy0f);
        const float wx0 = __fsub_rn(1.0f, wx1), wy0 = __fsub_rn(1.0f, wy1);
        const bool vx0 = (ix0f >= 0.0f) && (ix0f < 64.0f);
        const bool vx1 = (ix1f >= 0.0f) && (ix1f < 64.0f);
        const bool vy0 = (iy0f >= 0.0f) && (iy0f < 64.0f);
        const bool vy1 = (iy1f >= 0.0f) && (iy1f < 64.0f);
        const int x0  = (int)fminf(fmaxf(ix0f, 0.0f), 63.0f);
        const int x1  = (int)fminf(fmaxf(ix1f, 0.0f), 63.0f);
        const int y0i = (int)fminf(fmaxf(iy0f, 0.0f), 63.0f);
        const int y1i = (int)fminf(fmaxf(iy1f, 0.0f), 63.0f);
        const int r00 = y0i * 64 + x0, r01 = y0i * 64 + x1;
        const int r10 = y1i * 64 + x0, r11 = y1i * 64 + x1;
        const bool m00 = vy0 && vx0, m01 = vy0 && vx1, m10 = vy1 && vx0, m11 = vy1 && vx1;
        const float* img = decoded + ssamp[k] * 12288;

        float g00x = 0.f, g00y = 0.f, g00z = 0.f;
        float g01x = 0.f, g01y = 0.f, g01z = 0.f;
        float g10x = 0.f, g10y = 0.f, g10z = 0.f;
        float g11x = 0.f, g11y = 0.f, g11z = 0.f;
        if (m00) { const float* p = img + r00 * 3; g00x = p[0]; g00y = p[1]; g00z = p[2]; }
        if (m01) { const float* p = img + r01 * 3; g01x = p[0]; g01y = p[1]; g01z = p[2]; }
        if (m10) { const float* p = img + r10 * 3; g10x = p[0]; g10y = p[1]; g10z = p[2]; }
        if (m11) { const float* p = img + r11 * 3; g11x = p[0]; g11y = p[1]; g11z = p[2]; }

        if (!d0) {
            float val = g00x * wy0 * wx0 + g01x * wy0 * wx1 + g10x * wy1 * wx0 + g11x * wy1 * wx1;
            if (val != 0.0f) { o0 = val; d0 = true; }
        }
        if (!d1) {
            float val = g00y * wy0 * wx0 + g01y * wy0 * wx1 + g10y * wy1 * wx0 + g11y * wy1 * wx1;
            if (val != 0.0f) { o1 = val; d1 = true; }
        }
        if (!d2) {
            float val = g00z * wy0 * wx0 + g01z * wy0 * wx1 + g10z * wy1 * wx0 + g11z * wy1 * wx1;
            if (val != 0.0f) { o2 = val; d2 = true; }
        }
        if (d0 && d1 && d2) break;
    }
    const int ob = b * 270000 + pix;
    out[ob] = o0;
    out[ob + 90000] = o1;
    out[ob + 180000] = o2;
}

extern "C" void kernel_launch(void* const* d_in, const int* in_sizes, int n_in,
                              void* d_out, int out_size, void* d_ws, size_t ws_size,
                              hipStream_t stream)
{
    const float* z_what    = (const float*)d_in[0];
    const float* z_where   = (const float*)d_in[1];
    const int*   z_present = (const int*)d_in[2];
    const float* z_depth   = (const float*)d_in[3];
    const float* W0 = (const float*)d_in[4];   const float* b0 = (const float*)d_in[5];
    const float* W1 = (const float*)d_in[6];   const float* b1 = (const float*)d_in[7];
    const float* W2 = (const float*)d_in[8];   const float* b2 = (const float*)d_in[9];
    const float* W3 = (const float*)d_in[10];  const float* b3 = (const float*)d_in[11];
    const float* W4 = (const float*)d_in[12];  const float* b4 = (const float*)d_in[13];
    const float* W5 = (const float*)d_in[14];  const float* b5 = (const float*)d_in[15];

    float* ws = (float*)d_ws;
    float* gathered = ws;                       // 160*64    = 10240 floats
    float* paramsF  = ws + 16384;               // 640 floats
    int*   paramsI  = (int*)(ws + 17408);       // 192 ints
    float* decoded  = ws + 32768;               // 160*12288 floats, channel-last (~8 MB total)
    float* outp     = (float*)d_out;

    hipLaunchKernelGGL(topk_kernel, dim3(BATCH), dim3(256), 0, stream,
                       z_what, z_where, z_present, z_depth, gathered, paramsF, paramsI);
    hipLaunchKernelGGL(dec_fused, dim3(4, BATCH * KOBJ), dim3(256), 0, stream,
                       gathered, W0, b0, W1, b1, W2, b2, W3, b3, W4, b4, W5, b5, decoded);
    hipLaunchKernelGGL(stn_kernel, dim3(352, BATCH), dim3(256), 0, stream,
                       decoded, paramsF, paramsI, outp);
}

// Round 4
// 165.576 us; speedup vs baseline: 1.1752x; 1.1736x over previous
//
#include <hip/hip_runtime.h>
#include <cmath>

#define NLOC 1940
#define NPRI 8732
#define BATCH 16
#define KOBJ 10

// prior index -> location index (matches _recon_indices)
__device__ __forceinline__ int loc_of_prior(int p) {
    if (p < 5776) return p >> 2;                       // fm 38, bpl 4
    if (p < 7942) return 1444 + (p - 5776) / 6;        // fm 19, bpl 6
    if (p < 8542) return 1805 + (p - 7942) / 6;        // fm 10, bpl 6
    if (p < 8692) return 1905 + (p - 8542) / 6;        // fm 5,  bpl 6
    if (p < 8728) return 1930 + ((p - 8692) >> 2);     // fm 3,  bpl 4
    return 1939 + ((p - 8728) >> 2);                   // fm 1,  bpl 4
}

// ---------------------------------------------------------------------------
// Kernel 1: per-batch top-10 priors by depth (stable: value desc, index asc),
// gather z_what (all 10), and emit compacted present-object STN params.
// (unchanged from round 3 — verified correct twice)
// ---------------------------------------------------------------------------
__global__ __launch_bounds__(256) void topk_kernel(
    const float* __restrict__ z_what, const float* __restrict__ z_where,
    const int* __restrict__ z_present, const float* __restrict__ z_depth,
    float* __restrict__ gathered, float* __restrict__ paramsF, int* __restrict__ paramsI)
{
    const int b = blockIdx.x, tid = threadIdx.x;
    __shared__ float zd[NPRI];
    __shared__ float rv[256];
    __shared__ int   ri[256];
    __shared__ int   ord[KOBJ];
    __shared__ int   locs[KOBJ];

    for (int p = tid; p < NPRI; p += 256) zd[p] = z_depth[b * NLOC + loc_of_prior(p)];
    __syncthreads();

    for (int k = 0; k < KOBJ; ++k) {
        float bv = -INFINITY; int bi = NPRI;
        for (int p = tid; p < NPRI; p += 256) {
            float v = zd[p];
            if (v > bv) { bv = v; bi = p; }
        }
        rv[tid] = bv; ri[tid] = bi;
        __syncthreads();
        for (int s = 128; s > 0; s >>= 1) {
            if (tid < s) {
                float v2 = rv[tid + s]; int i2 = ri[tid + s];
                if (v2 > rv[tid] || (v2 == rv[tid] && i2 < ri[tid])) { rv[tid] = v2; ri[tid] = i2; }
            }
            __syncthreads();
        }
        if (tid == 0) {
            int w = ri[0];
            ord[k] = w; locs[k] = loc_of_prior(w);
            zd[w] = -INFINITY;
        }
        __syncthreads();
    }

    for (int e = tid; e < KOBJ * 64; e += 256) {
        int k = e >> 6, c = e & 63;
        gathered[(b * KOBJ + k) * 64 + c] = z_what[(b * NLOC + locs[k]) * 64 + c];
    }

    if (tid == 0) {
        int cnt = 0;
        for (int k = 0; k < KOBJ; ++k) {
            int p = ord[k];
            if (z_present[b * NPRI + p] == 1) {
                const float* zw = z_where + (b * NPRI + p) * 4;
                float cx = zw[0], cy = zw[1], w_ = zw[2], h_ = zw[3];
                float* pf = paramsF + (b * KOBJ + cnt) * 4;
                pf[0] = __fadd_rn(w_, 1e-6f);
                pf[1] = __fadd_rn(h_, 1e-6f);
                pf[2] = __fsub_rn(__fmul_rn(2.0f, cx), 1.0f);
                pf[3] = __fsub_rn(__fmul_rn(2.0f, cy), 1.0f);
                paramsI[b * 12 + 2 + cnt] = b * KOBJ + k;
                cnt++;
            }
        }
        paramsI[b * 12] = cnt;
    }
}

// ---------------------------------------------------------------------------
// Weight repack: W0[64,256,2,2] -> W0r[q][c][o]  (65536 floats)
//                W1[256,128,2,2] -> W1r[p][c][o] (131072 floats)
// Wr lives in d_out (scratch until stn overwrites it). Grid = 768 x 256 exact.
// ---------------------------------------------------------------------------
__global__ __launch_bounds__(256) void repack_kernel(
    const float* __restrict__ W0, const float* __restrict__ W1, float* __restrict__ Wr)
{
    const int idx = blockIdx.x * 256 + threadIdx.x;
    if (idx < 65536) {
        int q = idx >> 14, rem = idx & 16383, c = rem >> 8, o = rem & 255;
        Wr[idx] = W0[(((c << 8) | o) << 2) + q];
    } else {
        int i2 = idx - 65536;
        int q = i2 >> 15, rem = i2 & 32767, c = rem >> 7, o = rem & 127;
        Wr[idx] = W1[(((c << 7) | o) << 2) + q];
    }
}

// ---------------------------------------------------------------------------
// Fused 6-layer decoder. Block = (L1-out pixel region, group of 4 samples).
// Deconv2x2-stride2 has no spatial overlap, so each L1-out px (y1,x1) evolves
// independently into final 16x16 region at (y1*16, x1*16). Activations in LDS,
// sample-minor [c][4s] so act reads are ds_read_b128 (mostly wave-broadcast);
// each weight load feeds 4 samples (FMA:load >= 4:1).
// ---------------------------------------------------------------------------
__global__ __launch_bounds__(256) void dec_fused(
    const float* __restrict__ gathered, const float* __restrict__ Wr,
    const float* __restrict__ b0v, const float* __restrict__ b1v,
    const float* __restrict__ W2, const float* __restrict__ b2v,
    const float* __restrict__ W3, const float* __restrict__ b3v,
    const float* __restrict__ W4, const float* __restrict__ b4v,
    const float* __restrict__ W5, const float* __restrict__ b5v,
    float* __restrict__ decoded)
{
    __shared__ __align__(16) float P[4096];   // ping: L0out(1024) / L2out(4096) / L4out(4096)
    __shared__ __align__(16) float Q[2048];   // pong: L1out(512) / L3out(2048)
    __shared__ __align__(16) float Zs[256];
    const int r  = blockIdx.x;                // 0..15: L1-out px
    const int g  = blockIdx.y;                // 0..39: sample group
    const int t  = threadIdx.x;
    const int y1 = r >> 2, x1 = r & 3;
    const int q0 = (y1 >> 1) * 2 + (x1 >> 1); // which L0-out px
    const int p1 = (y1 & 1) * 2 + (x1 & 1);   // W1 sub-position
    const int s4 = g * 4;

    Zs[t] = gathered[(s4 + (t & 3)) * 64 + (t >> 2)];
    __syncthreads();

    // ---- L0: o = t, acc over 64 z-channels ----
    {
        const float* w0 = Wr + q0 * 16384 + t;
        float bv = b0v[t];
        float4 acc = make_float4(bv, bv, bv, bv);
        #pragma unroll 8
        for (int c = 0; c < 64; ++c) {
            float w = w0[c << 8];
            float4 xs = *reinterpret_cast<const float4*>(Zs + (c << 2));
            acc.x = fmaf(xs.x, w, acc.x); acc.y = fmaf(xs.y, w, acc.y);
            acc.z = fmaf(xs.z, w, acc.z); acc.w = fmaf(xs.w, w, acc.w);
        }
        float4 rv = make_float4(fmaxf(acc.x, 0.f), fmaxf(acc.y, 0.f),
                                fmaxf(acc.z, 0.f), fmaxf(acc.w, 0.f));
        *reinterpret_cast<float4*>(P + (t << 2)) = rv;
    }
    __syncthreads();

    // ---- L1: o = t&127, c split by h = t>>7 ----
    {
        const int o = t & 127, h = t >> 7;
        const float* w1 = Wr + 65536 + p1 * 32768 + o;
        float4 acc;
        if (h == 0) { float bv = b1v[o]; acc = make_float4(bv, bv, bv, bv); }
        else        { acc = make_float4(0.f, 0.f, 0.f, 0.f); }
        const int cb = h << 7;
        #pragma unroll 8
        for (int c = 0; c < 128; ++c) {
            float w = w1[(cb + c) << 7];
            float4 xs = *reinterpret_cast<const float4*>(P + ((cb + c) << 2));
            acc.x = fmaf(xs.x, w, acc.x); acc.y = fmaf(xs.y, w, acc.y);
            acc.z = fmaf(xs.z, w, acc.z); acc.w = fmaf(xs.w, w, acc.w);
        }
        if (h == 1) *reinterpret_cast<float4*>(P + 1024 + (o << 2)) = acc;
        __syncthreads();
        if (h == 0) {
            float4 p2 = *reinterpret_cast<const float4*>(P + 1024 + (o << 2));
            acc.x += p2.x; acc.y += p2.y; acc.z += p2.z; acc.w += p2.w;
            float4 rv = make_float4(fmaxf(acc.x, 0.f), fmaxf(acc.y, 0.f),
                                    fmaxf(acc.z, 0.f), fmaxf(acc.w, 0.f));
            *reinterpret_cast<float4*>(Q + (o << 2)) = rv;
        }
    }
    __syncthreads();

    // ---- L2: feature f = t = co*4+pos, 128 in-ch ----
    {
        const float* w2 = W2 + t;
        float bv = b2v[t >> 2];
        float4 acc = make_float4(bv, bv, bv, bv);
        #pragma unroll 8
        for (int ci = 0; ci < 128; ++ci) {
            float w = w2[ci << 8];
            float4 xs = *reinterpret_cast<const float4*>(Q + (ci << 2));
            acc.x = fmaf(xs.x, w, acc.x); acc.y = fmaf(xs.y, w, acc.y);
            acc.z = fmaf(xs.z, w, acc.z); acc.w = fmaf(xs.w, w, acc.w);
        }
        float4 rv = make_float4(fmaxf(acc.x, 0.f), fmaxf(acc.y, 0.f),
                                fmaxf(acc.z, 0.f), fmaxf(acc.w, 0.f));
        *reinterpret_cast<float4*>(P + (t << 2)) = rv;   // [co][pos][s]
    }
    __syncthreads();

    // ---- L3: px = t&15 (4x4), co = {t>>4, t>>4 + 16}, 64 in-ch ----
    {
        const int px = t & 15, coa = t >> 4;
        const int ly = px >> 2, lx = px & 3;
        const int par = (ly >> 1) * 2 + (lx >> 1);
        const int wp  = (ly & 1) * 2 + (lx & 1);
        const float* w3 = W3 + coa * 4 + wp;
        float bva = b3v[coa], bvb = b3v[coa + 16];
        float4 a0 = make_float4(bva, bva, bva, bva);
        float4 a1 = make_float4(bvb, bvb, bvb, bvb);
        #pragma unroll 4
        for (int ci = 0; ci < 64; ++ci) {
            float4 xs = *reinterpret_cast<const float4*>(P + (ci << 4) + (par << 2));
            float wa = w3[ci << 7];
            float wb = w3[(ci << 7) + 64];
            a0.x = fmaf(xs.x, wa, a0.x); a0.y = fmaf(xs.y, wa, a0.y);
            a0.z = fmaf(xs.z, wa, a0.z); a0.w = fmaf(xs.w, wa, a0.w);
            a1.x = fmaf(xs.x, wb, a1.x); a1.y = fmaf(xs.y, wb, a1.y);
            a1.z = fmaf(xs.z, wb, a1.z); a1.w = fmaf(xs.w, wb, a1.w);
        }
        float4 r0 = make_float4(fmaxf(a0.x, 0.f), fmaxf(a0.y, 0.f),
                                fmaxf(a0.z, 0.f), fmaxf(a0.w, 0.f));
        float4 r1 = make_float4(fmaxf(a1.x, 0.f), fmaxf(a1.y, 0.f),
                                fmaxf(a1.z, 0.f), fmaxf(a1.w, 0.f));
        *reinterpret_cast<float4*>(Q + (coa << 6) + (px << 2)) = r0;
        *reinterpret_cast<float4*>(Q + ((coa + 16) << 6) + (px << 2)) = r1;
    }
    __syncthreads();

    // ---- L4: px = t&63 (8x8), co = t>>6 + {0,4,8,12}, 32 in-ch ----
    {
        const int px = t & 63, co0 = t >> 6;
        const int ly = px >> 3, lx = px & 7;
        const int par = (ly >> 1) * 4 + (lx >> 1);
        const int wp  = (ly & 1) * 2 + (lx & 1);
        const float* w4 = W4 + co0 * 4 + wp;
        float4 acc[4];
        #pragma unroll
        for (int k = 0; k < 4; ++k) {
            float bv = b4v[co0 + 4 * k];
            acc[k] = make_float4(bv, bv, bv, bv);
        }
        #pragma unroll 4
        for (int ci = 0; ci < 32; ++ci) {
            float4 xs = *reinterpret_cast<const float4*>(Q + (ci << 6) + (par << 2));
            #pragma unroll
            for (int k = 0; k < 4; ++k) {
                float w = w4[(ci << 6) + k * 16];
                acc[k].x = fmaf(xs.x, w, acc[k].x); acc[k].y = fmaf(xs.y, w, acc[k].y);
                acc[k].z = fmaf(xs.z, w, acc[k].z); acc[k].w = fmaf(xs.w, w, acc[k].w);
            }
        }
        #pragma unroll
        for (int k = 0; k < 4; ++k) {
            float4 rv = make_float4(fmaxf(acc[k].x, 0.f), fmaxf(acc[k].y, 0.f),
                                    fmaxf(acc[k].z, 0.f), fmaxf(acc[k].w, 0.f));
            *reinterpret_cast<float4*>(P + ((co0 + 4 * k) << 8) + (px << 2)) = rv;
        }
    }
    __syncthreads();

    // ---- L5: px = t (16x16), co = 0..2, 16 in-ch, sigmoid -> global ----
    {
        const int px = t;
        const int ly = px >> 4, lx = px & 15;
        const int par = (ly >> 1) * 8 + (lx >> 1);
        const int wp  = (ly & 1) * 2 + (lx & 1);
        const int gy = y1 * 16 + ly, gx = x1 * 16 + lx;
        const float* w5 = W5 + wp;
        float4 acc[3];
        #pragma unroll
        for (int c = 0; c < 3; ++c) {
            float bv = b5v[c];
            acc[c] = make_float4(bv, bv, bv, bv);
        }
        #pragma unroll 4
        for (int ci = 0; ci < 16; ++ci) {
            float4 xs = *reinterpret_cast<const float4*>(P + (ci << 8) + (par << 2));
            #pragma unroll
            for (int c = 0; c < 3; ++c) {
                float w = w5[ci * 12 + c * 4];
                acc[c].x = fmaf(xs.x, w, acc[c].x); acc[c].y = fmaf(xs.y, w, acc[c].y);
                acc[c].z = fmaf(xs.z, w, acc[c].z); acc[c].w = fmaf(xs.w, w, acc[c].w);
            }
        }
        const int pbase = (gy * 64 + gx) * 3;
        #pragma unroll
        for (int c = 0; c < 3; ++c) {
            float vs[4] = {acc[c].x, acc[c].y, acc[c].z, acc[c].w};
            #pragma unroll
            for (int s = 0; s < 4; ++s)
                decoded[(s4 + s) * 12288 + pbase + c] = 1.0f / (1.0f + expf(-vs[s]));
        }
    }
}

// ---------------------------------------------------------------------------
// STN + first-nonzero composite (unchanged from round 3 — bitwise-critical).
// ---------------------------------------------------------------------------
__global__ __launch_bounds__(256) void stn_kernel(
    const float* __restrict__ decoded, const float* __restrict__ paramsF,
    const int* __restrict__ paramsI, float* __restrict__ out)
{
    const int b = blockIdx.y;
    __shared__ float sp[KOBJ][4];
    __shared__ int ssamp[KOBJ];
    __shared__ int scnt;
    if (threadIdx.x == 0) scnt = paramsI[b * 12];
    if (threadIdx.x < KOBJ) {
        #pragma unroll
        for (int c = 0; c < 4; ++c) sp[threadIdx.x][c] = paramsF[(b * KOBJ + threadIdx.x) * 4 + c];
        ssamp[threadIdx.x] = paramsI[b * 12 + 2 + threadIdx.x];
    }
    __syncthreads();
    const int pix = blockIdx.x * 256 + threadIdx.x;
    if (pix >= 90000) return;
    const int y = pix / 300;
    const int x = pix - y * 300;
    const float xo = __fsub_rn(__fdiv_rn(__fadd_rn(__fmul_rn(2.0f, (float)x), 1.0f), 300.0f), 1.0f);
    const float yo = __fsub_rn(__fdiv_rn(__fadd_rn(__fmul_rn(2.0f, (float)y), 1.0f), 300.0f), 1.0f);

    float o0 = 0.0f, o1 = 0.0f, o2 = 0.0f;
    bool d0 = false, d1 = false, d2 = false;
    const int cnt = scnt;
    for (int k = 0; k < cnt; ++k) {
        const float u = __fdiv_rn(__fsub_rn(xo, sp[k][2]), sp[k][0]);
        const float v = __fdiv_rn(__fsub_rn(yo, sp[k][3]), sp[k][1]);
        const float ix = __fmul_rn(__fsub_rn(__fmul_rn(__fadd_rn(u, 1.0f), 64.0f), 1.0f), 0.5f);
        const float iy = __fmul_rn(__fsub_rn(__fmul_rn(__fadd_rn(v, 1.0f), 64.0f), 1.0f), 0.5f);
        if (!(ix > -1.0f && ix < 64.0f && iy > -1.0f && iy < 64.0f)) continue;

        const float ix0f = floorf(ix), iy0f = floorf(iy);
        const float ix1f = __fadd_rn(ix0f, 1.0f), iy1f = __fadd_rn(iy0f, 1.0f);
        const float wx1 = __fsub_rn(ix, ix0f), wy1 = __fsub_rn(iy, iy0f);
        const float wx0 = __fsub_rn(1.0f, wx1), wy0 = __fsub_rn(1.0f, wy1);
        const bool vx0 = (ix0f >= 0.0f) && (ix0f < 64.0f);
        const bool vx1 = (ix1f >= 0.0f) && (ix1f < 64.0f);
        const bool vy0 = (iy0f >= 0.0f) && (iy0f < 64.0f);
        const bool vy1 = (iy1f >= 0.0f) && (iy1f < 64.0f);
        const int x0  = (int)fminf(fmaxf(ix0f, 0.0f), 63.0f);
        const int x1  = (int)fminf(fmaxf(ix1f, 0.0f), 63.0f);
        const int y0i = (int)fminf(fmaxf(iy0f, 0.0f), 63.0f);
        const int y1i = (int)fminf(fmaxf(iy1f, 0.0f), 63.0f);
        const int r00 = y0i * 64 + x0, r01 = y0i * 64 + x1;
        const int r10 = y1i * 64 + x0, r11 = y1i * 64 + x1;
        const bool m00 = vy0 && vx0, m01 = vy0 && vx1, m10 = vy1 && vx0, m11 = vy1 && vx1;
        const float* img = decoded + ssamp[k] * 12288;

        float g00x = 0.f, g00y = 0.f, g00z = 0.f;
        float g01x = 0.f, g01y = 0.f, g01z = 0.f;
        float g10x = 0.f, g10y = 0.f, g10z = 0.f;
        float g11x = 0.f, g11y = 0.f, g11z = 0.f;
        if (m00) { const float* p = img + r00 * 3; g00x = p[0]; g00y = p[1]; g00z = p[2]; }
        if (m01) { const float* p = img + r01 * 3; g01x = p[0]; g01y = p[1]; g01z = p[2]; }
        if (m10) { const float* p = img + r10 * 3; g10x = p[0]; g10y = p[1]; g10z = p[2]; }
        if (m11) { const float* p = img + r11 * 3; g11x = p[0]; g11y = p[1]; g11z = p[2]; }

        if (!d0) {
            float val = g00x * wy0 * wx0 + g01x * wy0 * wx1 + g10x * wy1 * wx0 + g11x * wy1 * wx1;
            if (val != 0.0f) { o0 = val; d0 = true; }
        }
        if (!d1) {
            float val = g00y * wy0 * wx0 + g01y * wy0 * wx1 + g10y * wy1 * wx0 + g11y * wy1 * wx1;
            if (val != 0.0f) { o1 = val; d1 = true; }
        }
        if (!d2) {
            float val = g00z * wy0 * wx0 + g01z * wy0 * wx1 + g10z * wy1 * wx0 + g11z * wy1 * wx1;
            if (val != 0.0f) { o2 = val; d2 = true; }
        }
        if (d0 && d1 && d2) break;
    }
    const int ob = b * 270000 + pix;
    out[ob] = o0;
    out[ob + 90000] = o1;
    out[ob + 180000] = o2;
}

extern "C" void kernel_launch(void* const* d_in, const int* in_sizes, int n_in,
                              void* d_out, int out_size, void* d_ws, size_t ws_size,
                              hipStream_t stream)
{
    const float* z_what    = (const float*)d_in[0];
    const float* z_where   = (const float*)d_in[1];
    const int*   z_present = (const int*)d_in[2];
    const float* z_depth   = (const float*)d_in[3];
    const float* W0 = (const float*)d_in[4];   const float* b0 = (const float*)d_in[5];
    const float* W1 = (const float*)d_in[6];   const float* b1 = (const float*)d_in[7];
    const float* W2 = (const float*)d_in[8];   const float* b2 = (const float*)d_in[9];
    const float* W3 = (const float*)d_in[10];  const float* b3 = (const float*)d_in[11];
    const float* W4 = (const float*)d_in[12];  const float* b4 = (const float*)d_in[13];
    const float* W5 = (const float*)d_in[14];  const float* b5 = (const float*)d_in[15];

    float* ws = (float*)d_ws;
    float* gathered = ws;                       // 160*64 floats
    float* paramsF  = ws + 16384;               // 640 floats
    int*   paramsI  = (int*)(ws + 17408);       // 192 ints
    float* decoded  = ws + 32768;               // 160*12288 floats, channel-last
    float* Wr       = (float*)d_out;            // 196608 floats scratch (stn overwrites later)
    float* outp     = (float*)d_out;

    hipLaunchKernelGGL(repack_kernel, dim3(768), dim3(256), 0, stream, W0, W1, Wr);
    hipLaunchKernelGGL(topk_kernel, dim3(BATCH), dim3(256), 0, stream,
                       z_what, z_where, z_present, z_depth, gathered, paramsF, paramsI);
    hipLaunchKernelGGL(dec_fused, dim3(16, 40), dim3(256), 0, stream,
                       gathered, Wr, b0, b1, W2, b2, W3, b3, W4, b4, W5, b5, decoded);
    hipLaunchKernelGGL(stn_kernel, dim3(352, BATCH), dim3(256), 0, stream,
                       decoded, paramsF, paramsI, outp);
}

// Round 5
// 150.509 us; speedup vs baseline: 1.2929x; 1.1001x over previous
//
#include <hip/hip_runtime.h>
#include <cmath>

#define NLOC 1940
#define NPRI 8732
#define BATCH 16
#define KOBJ 10

// insert (v,i) into sorted-3 list (value desc, index asc — stable-argsort order)
__device__ __forceinline__ void ins3(float v, int i,
    float& a0, float& a1, float& a2, int& j0, int& j1, int& j2)
{
    if (v > a0 || (v == a0 && i < j0)) { a2=a1; j2=j1; a1=a0; j1=j0; a0=v; j0=i; }
    else if (v > a1 || (v == a1 && i < j1)) { a2=a1; j2=j1; a1=v; j1=i; }
    else if (v > a2 || (v == a2 && i < j2)) { a2=v; j2=i; }
}

// ---------------------------------------------------------------------------
// prep_kernel: blocks 0..767 repack W0/W1 into Wr[pos][c][o] (in d_out scratch);
// blocks 768..783: per-batch top-3 LOCATIONS by depth (z_depth is per-location;
// priors repeat locations 4-6x, so top-10 priors = top-3 locations expanded by
// bpl in stable-argsort order), gather z_what (<=3 per batch), emit compacted
// present-object STN params with image idx = b*3 + loc-rank.
// ---------------------------------------------------------------------------
__global__ __launch_bounds__(256) void prep_kernel(
    const float* __restrict__ W0, const float* __restrict__ W1, float* __restrict__ Wr,
    const float* __restrict__ z_what, const float* __restrict__ z_where,
    const int* __restrict__ z_present, const float* __restrict__ z_depth,
    float* __restrict__ gathered, float* __restrict__ paramsF, int* __restrict__ paramsI)
{
    __shared__ float sv[768];
    __shared__ int   si[768];
    __shared__ int   locs3[3];
    const int tid = threadIdx.x;

    if (blockIdx.x < 768) {
        const int idx = blockIdx.x * 256 + tid;
        if (idx < 65536) {
            int q = idx >> 14, rem = idx & 16383, c = rem >> 8, o = rem & 255;
            Wr[idx] = W0[(((c << 8) | o) << 2) + q];
        } else {
            int i2 = idx - 65536;
            int q = i2 >> 15, rem = i2 & 32767, c = rem >> 7, o = rem & 127;
            Wr[idx] = W1[(((c << 7) | o) << 2) + q];
        }
        return;
    }

    const int b = blockIdx.x - 768;
    // per-thread top-3 over strided locations
    float v0 = -INFINITY, v1 = -INFINITY, v2 = -INFINITY;
    int   i0 = NLOC, i1 = NLOC, i2 = NLOC;
    for (int i = tid; i < NLOC; i += 256) {
        float v = z_depth[b * NLOC + i];
        ins3(v, i, v0, v1, v2, i0, i1, i2);
    }
    sv[tid*3+0] = v0; sv[tid*3+1] = v1; sv[tid*3+2] = v2;
    si[tid*3+0] = i0; si[tid*3+1] = i1; si[tid*3+2] = i2;
    __syncthreads();
    for (int s = 128; s > 0; s >>= 1) {
        if (tid < s) {
            float a0 = sv[tid*3], a1 = sv[tid*3+1], a2 = sv[tid*3+2];
            int   j0 = si[tid*3], j1 = si[tid*3+1], j2 = si[tid*3+2];
            const int o = tid + s;
            ins3(sv[o*3+0], si[o*3+0], a0, a1, a2, j0, j1, j2);
            ins3(sv[o*3+1], si[o*3+1], a0, a1, a2, j0, j1, j2);
            ins3(sv[o*3+2], si[o*3+2], a0, a1, a2, j0, j1, j2);
            sv[tid*3] = a0; sv[tid*3+1] = a1; sv[tid*3+2] = a2;
            si[tid*3] = j0; si[tid*3+1] = j1; si[tid*3+2] = j2;
        }
        __syncthreads();
    }

    if (tid == 0) {
        int cnt = 0, taken = 0;
        for (int j = 0; j < 3; ++j) {
            int L = si[j];
            locs3[j] = L;
            if (taken >= KOBJ) continue;
            int start, bpl;
            if (L < 1444)      { start = 4 * L;                 bpl = 4; }
            else if (L < 1805) { start = 5776 + 6 * (L - 1444); bpl = 6; }
            else if (L < 1905) { start = 7942 + 6 * (L - 1805); bpl = 6; }
            else if (L < 1930) { start = 8542 + 6 * (L - 1905); bpl = 6; }
            else if (L < 1939) { start = 8692 + 4 * (L - 1930); bpl = 4; }
            else               { start = 8728;                  bpl = 4; }
            for (int o = 0; o < bpl && taken < KOBJ; ++o, ++taken) {
                int p = start + o;
                if (z_present[b * NPRI + p] == 1) {
                    const float* zw = z_where + (b * NPRI + p) * 4;
                    float cx = zw[0], cy = zw[1], w_ = zw[2], h_ = zw[3];
                    float* pf = paramsF + (b * KOBJ + cnt) * 4;
                    pf[0] = __fadd_rn(w_, 1e-6f);
                    pf[1] = __fadd_rn(h_, 1e-6f);
                    pf[2] = __fsub_rn(__fmul_rn(2.0f, cx), 1.0f);
                    pf[3] = __fsub_rn(__fmul_rn(2.0f, cy), 1.0f);
                    paramsI[b * 12 + 2 + cnt] = b * 3 + j;   // dedup'ed image idx
                    cnt++;
                }
            }
        }
        paramsI[b * 12] = cnt;
    }
    __syncthreads();
    if (tid < 192) {
        int j = tid >> 6, c = tid & 63;
        gathered[(b * 3 + j) * 64 + c] = z_what[(b * NLOC + locs3[j]) * 64 + c];
    }
}

// ---------------------------------------------------------------------------
// Fused 6-layer decoder over 48 dedup'ed samples (16 batches x <=3 locations).
// Block = (L1-out pixel region, group of 4 samples); activations in LDS,
// sample-minor [c][4s]; each weight load feeds 4 samples.
// ---------------------------------------------------------------------------
__global__ __launch_bounds__(256) void dec_fused(
    const float* __restrict__ gathered, const float* __restrict__ Wr,
    const float* __restrict__ b0v, const float* __restrict__ b1v,
    const float* __restrict__ W2, const float* __restrict__ b2v,
    const float* __restrict__ W3, const float* __restrict__ b3v,
    const float* __restrict__ W4, const float* __restrict__ b4v,
    const float* __restrict__ W5, const float* __restrict__ b5v,
    float* __restrict__ decoded)
{
    __shared__ __align__(16) float P[4096];
    __shared__ __align__(16) float Q[2048];
    __shared__ __align__(16) float Zs[256];
    const int r  = blockIdx.x;                // 0..15: L1-out px
    const int g  = blockIdx.y;                // 0..11: sample group (48 samples)
    const int t  = threadIdx.x;
    const int y1 = r >> 2, x1 = r & 3;
    const int q0 = (y1 >> 1) * 2 + (x1 >> 1);
    const int p1 = (y1 & 1) * 2 + (x1 & 1);
    const int s4 = g * 4;

    Zs[t] = gathered[(s4 + (t & 3)) * 64 + (t >> 2)];
    __syncthreads();

    // ---- L0 ----
    {
        const float* w0 = Wr + q0 * 16384 + t;
        float bv = b0v[t];
        float4 acc = make_float4(bv, bv, bv, bv);
        #pragma unroll 8
        for (int c = 0; c < 64; ++c) {
            float w = w0[c << 8];
            float4 xs = *reinterpret_cast<const float4*>(Zs + (c << 2));
            acc.x = fmaf(xs.x, w, acc.x); acc.y = fmaf(xs.y, w, acc.y);
            acc.z = fmaf(xs.z, w, acc.z); acc.w = fmaf(xs.w, w, acc.w);
        }
        *reinterpret_cast<float4*>(P + (t << 2)) =
            make_float4(fmaxf(acc.x, 0.f), fmaxf(acc.y, 0.f), fmaxf(acc.z, 0.f), fmaxf(acc.w, 0.f));
    }
    __syncthreads();

    // ---- L1 ----
    {
        const int o = t & 127, h = t >> 7;
        const float* w1 = Wr + 65536 + p1 * 32768 + o;
        float4 acc;
        if (h == 0) { float bv = b1v[o]; acc = make_float4(bv, bv, bv, bv); }
        else        { acc = make_float4(0.f, 0.f, 0.f, 0.f); }
        const int cb = h << 7;
        #pragma unroll 8
        for (int c = 0; c < 128; ++c) {
            float w = w1[(cb + c) << 7];
            float4 xs = *reinterpret_cast<const float4*>(P + ((cb + c) << 2));
            acc.x = fmaf(xs.x, w, acc.x); acc.y = fmaf(xs.y, w, acc.y);
            acc.z = fmaf(xs.z, w, acc.z); acc.w = fmaf(xs.w, w, acc.w);
        }
        if (h == 1) *reinterpret_cast<float4*>(P + 1024 + (o << 2)) = acc;
        __syncthreads();
        if (h == 0) {
            float4 p2 = *reinterpret_cast<const float4*>(P + 1024 + (o << 2));
            acc.x += p2.x; acc.y += p2.y; acc.z += p2.z; acc.w += p2.w;
            *reinterpret_cast<float4*>(Q + (o << 2)) =
                make_float4(fmaxf(acc.x, 0.f), fmaxf(acc.y, 0.f), fmaxf(acc.z, 0.f), fmaxf(acc.w, 0.f));
        }
    }
    __syncthreads();

    // ---- L2 ----
    {
        const float* w2 = W2 + t;
        float bv = b2v[t >> 2];
        float4 acc = make_float4(bv, bv, bv, bv);
        #pragma unroll 8
        for (int ci = 0; ci < 128; ++ci) {
            float w = w2[ci << 8];
            float4 xs = *reinterpret_cast<const float4*>(Q + (ci << 2));
            acc.x = fmaf(xs.x, w, acc.x); acc.y = fmaf(xs.y, w, acc.y);
            acc.z = fmaf(xs.z, w, acc.z); acc.w = fmaf(xs.w, w, acc.w);
        }
        *reinterpret_cast<float4*>(P + (t << 2)) =
            make_float4(fmaxf(acc.x, 0.f), fmaxf(acc.y, 0.f), fmaxf(acc.z, 0.f), fmaxf(acc.w, 0.f));
    }
    __syncthreads();

    // ---- L3 ----
    {
        const int px = t & 15, coa = t >> 4;
        const int ly = px >> 2, lx = px & 3;
        const int par = (ly >> 1) * 2 + (lx >> 1);
        const int wp  = (ly & 1) * 2 + (lx & 1);
        const float* w3 = W3 + coa * 4 + wp;
        float bva = b3v[coa], bvb = b3v[coa + 16];
        float4 a0 = make_float4(bva, bva, bva, bva);
        float4 a1 = make_float4(bvb, bvb, bvb, bvb);
        #pragma unroll 4
        for (int ci = 0; ci < 64; ++ci) {
            float4 xs = *reinterpret_cast<const float4*>(P + (ci << 4) + (par << 2));
            float wa = w3[ci << 7];
            float wb = w3[(ci << 7) + 64];
            a0.x = fmaf(xs.x, wa, a0.x); a0.y = fmaf(xs.y, wa, a0.y);
            a0.z = fmaf(xs.z, wa, a0.z); a0.w = fmaf(xs.w, wa, a0.w);
            a1.x = fmaf(xs.x, wb, a1.x); a1.y = fmaf(xs.y, wb, a1.y);
            a1.z = fmaf(xs.z, wb, a1.z); a1.w = fmaf(xs.w, wb, a1.w);
        }
        *reinterpret_cast<float4*>(Q + (coa << 6) + (px << 2)) =
            make_float4(fmaxf(a0.x, 0.f), fmaxf(a0.y, 0.f), fmaxf(a0.z, 0.f), fmaxf(a0.w, 0.f));
        *reinterpret_cast<float4*>(Q + ((coa + 16) << 6) + (px << 2)) =
            make_float4(fmaxf(a1.x, 0.f), fmaxf(a1.y, 0.f), fmaxf(a1.z, 0.f), fmaxf(a1.w, 0.f));
    }
    __syncthreads();

    // ---- L4 ----
    {
        const int px = t & 63, co0 = t >> 6;
        const int ly = px >> 3, lx = px & 7;
        const int par = (ly >> 1) * 4 + (lx >> 1);
        const int wp  = (ly & 1) * 2 + (lx & 1);
        const float* w4 = W4 + co0 * 4 + wp;
        float4 acc[4];
        #pragma unroll
        for (int k = 0; k < 4; ++k) {
            float bv = b4v[co0 + 4 * k];
            acc[k] = make_float4(bv, bv, bv, bv);
        }
        #pragma unroll 4
        for (int ci = 0; ci < 32; ++ci) {
            float4 xs = *reinterpret_cast<const float4*>(Q + (ci << 6) + (par << 2));
            #pragma unroll
            for (int k = 0; k < 4; ++k) {
                float w = w4[(ci << 6) + k * 16];
                acc[k].x = fmaf(xs.x, w, acc[k].x); acc[k].y = fmaf(xs.y, w, acc[k].y);
                acc[k].z = fmaf(xs.z, w, acc[k].z); acc[k].w = fmaf(xs.w, w, acc[k].w);
            }
        }
        #pragma unroll
        for (int k = 0; k < 4; ++k) {
            *reinterpret_cast<float4*>(P + ((co0 + 4 * k) << 8) + (px << 2)) =
                make_float4(fmaxf(acc[k].x, 0.f), fmaxf(acc[k].y, 0.f),
                            fmaxf(acc[k].z, 0.f), fmaxf(acc[k].w, 0.f));
        }
    }
    __syncthreads();

    // ---- L5: sigmoid -> global channel-last ----
    {
        const int px = t;
        const int ly = px >> 4, lx = px & 15;
        const int par = (ly >> 1) * 8 + (lx >> 1);
        const int wp  = (ly & 1) * 2 + (lx & 1);
        const int gy = y1 * 16 + ly, gx = x1 * 16 + lx;
        const float* w5 = W5 + wp;
        float4 acc[3];
        #pragma unroll
        for (int c = 0; c < 3; ++c) {
            float bv = b5v[c];
            acc[c] = make_float4(bv, bv, bv, bv);
        }
        #pragma unroll 4
        for (int ci = 0; ci < 16; ++ci) {
            float4 xs = *reinterpret_cast<const float4*>(P + (ci << 8) + (par << 2));
            #pragma unroll
            for (int c = 0; c < 3; ++c) {
                float w = w5[ci * 12 + c * 4];
                acc[c].x = fmaf(xs.x, w, acc[c].x); acc[c].y = fmaf(xs.y, w, acc[c].y);
                acc[c].z = fmaf(xs.z, w, acc[c].z); acc[c].w = fmaf(xs.w, w, acc[c].w);
            }
        }
        const int pbase = (gy * 64 + gx) * 3;
        #pragma unroll
        for (int c = 0; c < 3; ++c) {
            float vs[4] = {acc[c].x, acc[c].y, acc[c].z, acc[c].w};
            #pragma unroll
            for (int s = 0; s < 4; ++s)
                decoded[(s4 + s) * 12288 + pbase + c] = 1.0f / (1.0f + expf(-vs[s]));
        }
    }
}

// ---------------------------------------------------------------------------
// STN + first-nonzero composite. A 256-px block spans <=2 rows: y-geometry
// (bitwise-identical op chain) is computed once per (object,row); objects
// covering neither row are culled for the whole block. Per-pixel loop runs
// only the x-chain + masked 12B gathers.
// ---------------------------------------------------------------------------
__global__ __launch_bounds__(256) void stn_kernel(
    const float* __restrict__ decoded, const float* __restrict__ paramsF,
    const int* __restrict__ paramsI, float* __restrict__ out)
{
    const int b = blockIdx.y;
    const int pix0 = blockIdx.x * 256;
    const int yfirst = pix0 / 300;
    __shared__ float sp[KOBJ][4];
    __shared__ int   ssamp[KOBJ];
    __shared__ int   scnt;
    __shared__ float s_wy0[KOBJ][2], s_wy1[KOBJ][2];
    __shared__ int   s_rb0[KOBJ][2], s_rb1[KOBJ][2];
    __shared__ unsigned char s_cov[KOBJ][2];
    __shared__ unsigned char s_vy[KOBJ][2];    // bit0 = vy0, bit1 = vy1
    __shared__ int s_list[KOBJ];
    __shared__ int s_lc;
    const int tid = threadIdx.x;

    if (tid == 0) scnt = paramsI[b * 12];
    if (tid < KOBJ) {
        #pragma unroll
        for (int c = 0; c < 4; ++c) sp[tid][c] = paramsF[(b * KOBJ + tid) * 4 + c];
        ssamp[tid] = paramsI[b * 12 + 2 + tid];
    }
    __syncthreads();

    if (tid < 2 * scnt) {
        const int k = tid >> 1, sel = tid & 1;
        int yy = yfirst + sel; if (yy > 299) yy = 299;
        const float yo = __fsub_rn(__fdiv_rn(__fadd_rn(__fmul_rn(2.0f, (float)yy), 1.0f), 300.0f), 1.0f);
        const float v  = __fdiv_rn(__fsub_rn(yo, sp[k][3]), sp[k][1]);
        const float iy = __fmul_rn(__fsub_rn(__fmul_rn(__fadd_rn(v, 1.0f), 64.0f), 1.0f), 0.5f);
        const bool cov = (iy > -1.0f && iy < 64.0f);
        s_cov[k][sel] = cov ? 1 : 0;
        const float iy0f = floorf(iy);
        const float iy1f = __fadd_rn(iy0f, 1.0f);
        const float wy1  = __fsub_rn(iy, iy0f);
        s_wy1[k][sel] = wy1;
        s_wy0[k][sel] = __fsub_rn(1.0f, wy1);
        const bool vy0 = (iy0f >= 0.0f) && (iy0f < 64.0f);
        const bool vy1 = (iy1f >= 0.0f) && (iy1f < 64.0f);
        s_vy[k][sel] = (unsigned char)((vy0 ? 1 : 0) | (vy1 ? 2 : 0));
        s_rb0[k][sel] = ((int)fminf(fmaxf(iy0f, 0.0f), 63.0f)) * 64;
        s_rb1[k][sel] = ((int)fminf(fmaxf(iy1f, 0.0f), 63.0f)) * 64;
    }
    __syncthreads();
    if (tid == 0) {
        int lc = 0;
        for (int k = 0; k < scnt; ++k)
            if (s_cov[k][0] | s_cov[k][1]) s_list[lc++] = k;
        s_lc = lc;
    }
    __syncthreads();

    const int pix = pix0 + tid;
    if (pix < 90000) {
        const int y = pix / 300;
        const int x = pix - y * 300;
        const int rs = y - yfirst;
        const float xo = __fsub_rn(__fdiv_rn(__fadd_rn(__fmul_rn(2.0f, (float)x), 1.0f), 300.0f), 1.0f);

        float o0 = 0.0f, o1 = 0.0f, o2 = 0.0f;
        bool d0 = false, d1 = false, d2 = false;
        const int lc = s_lc;
        for (int m = 0; m < lc; ++m) {
            const int k = s_list[m];
            if (!s_cov[k][rs]) continue;
            const float u  = __fdiv_rn(__fsub_rn(xo, sp[k][2]), sp[k][0]);
            const float ix = __fmul_rn(__fsub_rn(__fmul_rn(__fadd_rn(u, 1.0f), 64.0f), 1.0f), 0.5f);
            if (!(ix > -1.0f && ix < 64.0f)) continue;

            const float ix0f = floorf(ix);
            const float ix1f = __fadd_rn(ix0f, 1.0f);
            const float wx1 = __fsub_rn(ix, ix0f);
            const float wx0 = __fsub_rn(1.0f, wx1);
            const bool vx0 = (ix0f >= 0.0f) && (ix0f < 64.0f);
            const bool vx1 = (ix1f >= 0.0f) && (ix1f < 64.0f);
            const int x0 = (int)fminf(fmaxf(ix0f, 0.0f), 63.0f);
            const int x1 = (int)fminf(fmaxf(ix1f, 0.0f), 63.0f);

            const float wy0 = s_wy0[k][rs], wy1 = s_wy1[k][rs];
            const int rb0 = s_rb0[k][rs], rb1 = s_rb1[k][rs];
            const unsigned char vy = s_vy[k][rs];
            const bool m00 = (vy & 1) && vx0, m01 = (vy & 1) && vx1;
            const bool m10 = (vy & 2) && vx0, m11 = (vy & 2) && vx1;
            const float* img = decoded + ssamp[k] * 12288;

            float g00x = 0.f, g00y = 0.f, g00z = 0.f;
            float g01x = 0.f, g01y = 0.f, g01z = 0.f;
            float g10x = 0.f, g10y = 0.f, g10z = 0.f;
            float g11x = 0.f, g11y = 0.f, g11z = 0.f;
            if (m00) { const float* p = img + (rb0 + x0) * 3; g00x = p[0]; g00y = p[1]; g00z = p[2]; }
            if (m01) { const float* p = img + (rb0 + x1) * 3; g01x = p[0]; g01y = p[1]; g01z = p[2]; }
            if (m10) { const float* p = img + (rb1 + x0) * 3; g10x = p[0]; g10y = p[1]; g10z = p[2]; }
            if (m11) { const float* p = img + (rb1 + x1) * 3; g11x = p[0]; g11y = p[1]; g11z = p[2]; }

            if (!d0) {
                float val = g00x * wy0 * wx0 + g01x * wy0 * wx1 + g10x * wy1 * wx0 + g11x * wy1 * wx1;
                if (val != 0.0f) { o0 = val; d0 = true; }
            }
            if (!d1) {
                float val = g00y * wy0 * wx0 + g01y * wy0 * wx1 + g10y * wy1 * wx0 + g11y * wy1 * wx1;
                if (val != 0.0f) { o1 = val; d1 = true; }
            }
            if (!d2) {
                float val = g00z * wy0 * wx0 + g01z * wy0 * wx1 + g10z * wy1 * wx0 + g11z * wy1 * wx1;
                if (val != 0.0f) { o2 = val; d2 = true; }
            }
            if (d0 && d1 && d2) break;
        }
        const int ob = b * 270000 + pix;
        out[ob] = o0;
        out[ob + 90000] = o1;
        out[ob + 180000] = o2;
    }
}

extern "C" void kernel_launch(void* const* d_in, const int* in_sizes, int n_in,
                              void* d_out, int out_size, void* d_ws, size_t ws_size,
                              hipStream_t stream)
{
    const float* z_what    = (const float*)d_in[0];
    const float* z_where   = (const float*)d_in[1];
    const int*   z_present = (const int*)d_in[2];
    const float* z_depth   = (const float*)d_in[3];
    const float* W0 = (const float*)d_in[4];   const float* b0 = (const float*)d_in[5];
    const float* W1 = (const float*)d_in[6];   const float* b1 = (const float*)d_in[7];
    const float* W2 = (const float*)d_in[8];   const float* b2 = (const float*)d_in[9];
    const float* W3 = (const float*)d_in[10];  const float* b3 = (const float*)d_in[11];
    const float* W4 = (const float*)d_in[12];  const float* b4 = (const float*)d_in[13];
    const float* W5 = (const float*)d_in[14];  const float* b5 = (const float*)d_in[15];

    float* ws = (float*)d_ws;
    float* gathered = ws;                       // 48*64 floats
    float* paramsF  = ws + 16384;               // 640 floats
    int*   paramsI  = (int*)(ws + 17408);       // 192 ints
    float* decoded  = ws + 32768;               // 48*12288 floats, channel-last (~2.4 MB)
    float* Wr       = (float*)d_out;            // 196608 floats scratch (stn overwrites later)
    float* outp     = (float*)d_out;

    hipLaunchKernelGGL(prep_kernel, dim3(784), dim3(256), 0, stream,
                       W0, W1, Wr, z_what, z_where, z_present, z_depth,
                       gathered, paramsF, paramsI);
    hipLaunchKernelGGL(dec_fused, dim3(16, 12), dim3(256), 0, stream,
                       gathered, Wr, b0, b1, W2, b2, W3, b3, W4, b4, W5, b5, decoded);
    hipLaunchKernelGGL(stn_kernel, dim3(352, BATCH), dim3(256), 0, stream,
                       decoded, paramsF, paramsI, outp);
}

// Round 6
// 148.855 us; speedup vs baseline: 1.3073x; 1.0111x over previous
//
#include <hip/hip_runtime.h>
#include <cmath>

#define NLOC 1940
#define NPRI 8732
#define BATCH 16
#define KOBJ 10

// insert (v,i) into sorted-3 list (value desc, index asc — stable-argsort order)
__device__ __forceinline__ void ins3(float v, int i,
    float& a0, float& a1, float& a2, int& j0, int& j1, int& j2)
{
    if (v > a0 || (v == a0 && i < j0)) { a2=a1; j2=j1; a1=a0; j1=j0; a0=v; j0=i; }
    else if (v > a1 || (v == a1 && i < j1)) { a2=a1; j2=j1; a1=v; j1=i; }
    else if (v > a2 || (v == a2 && i < j2)) { a2=v; j2=i; }
}

// EXACT reference geometry chain: pixel index -> sampling coord (bitwise = ref)
__device__ __forceinline__ float ix_chain(int x, float shift, float wh) {
    const float xo = __fsub_rn(__fdiv_rn(__fadd_rn(__fmul_rn(2.0f, (float)x), 1.0f), 300.0f), 1.0f);
    const float u  = __fdiv_rn(__fsub_rn(xo, shift), wh);
    return __fmul_rn(__fsub_rn(__fmul_rn(__fadd_rn(u, 1.0f), 64.0f), 1.0f), 0.5f);
}

// ---------------------------------------------------------------------------
// prep_kernel: blocks 0..767 repack W0/W1 into Wr[pos][c][o];
// blocks 768..783: per-batch top-3 LOCATIONS by depth (priors repeat locations
// 4-6x -> top-10 priors = top-3 locations expanded in stable order), candidate
// priors loaded in parallel, compacted present-object STN params, and EXACT
// integer coverage intervals per object via binary search on the bitwise chain
// (ix monotone in x because w+eps > 0).
// ---------------------------------------------------------------------------
__global__ __launch_bounds__(256) void prep_kernel(
    const float* __restrict__ W0, const float* __restrict__ W1, float* __restrict__ Wr,
    const float* __restrict__ z_what, const float* __restrict__ z_where,
    const int* __restrict__ z_present, const float* __restrict__ z_depth,
    float* __restrict__ gathered, float* __restrict__ paramsF, int* __restrict__ paramsI,
    int* __restrict__ obnd)
{
    __shared__ float sv[768];
    __shared__ int   si[768];
    __shared__ int   locs3[3];
    __shared__ int   sj_start[3], sj_bpl[3];
    __shared__ int   spres[10], sjj[10];
    __shared__ float szw[10][4];
    __shared__ float lpf[KOBJ][4];
    __shared__ int   lcnt;
    const int tid = threadIdx.x;

    if (blockIdx.x < 768) {
        const int idx = blockIdx.x * 256 + tid;
        if (idx < 65536) {
            int q = idx >> 14, rem = idx & 16383, c = rem >> 8, o = rem & 255;
            Wr[idx] = W0[(((c << 8) | o) << 2) + q];
        } else {
            int i2 = idx - 65536;
            int q = i2 >> 15, rem = i2 & 32767, c = rem >> 7, o = rem & 127;
            Wr[idx] = W1[(((c << 7) | o) << 2) + q];
        }
        return;
    }

    const int b = blockIdx.x - 768;
    float v0 = -INFINITY, v1 = -INFINITY, v2 = -INFINITY;
    int   i0 = NLOC, i1 = NLOC, i2 = NLOC;
    for (int i = tid; i < NLOC; i += 256) {
        float v = z_depth[b * NLOC + i];
        ins3(v, i, v0, v1, v2, i0, i1, i2);
    }
    sv[tid*3+0] = v0; sv[tid*3+1] = v1; sv[tid*3+2] = v2;
    si[tid*3+0] = i0; si[tid*3+1] = i1; si[tid*3+2] = i2;
    __syncthreads();
    for (int s = 128; s > 0; s >>= 1) {
        if (tid < s) {
            float a0 = sv[tid*3], a1 = sv[tid*3+1], a2 = sv[tid*3+2];
            int   j0 = si[tid*3], j1 = si[tid*3+1], j2 = si[tid*3+2];
            const int o = tid + s;
            ins3(sv[o*3+0], si[o*3+0], a0, a1, a2, j0, j1, j2);
            ins3(sv[o*3+1], si[o*3+1], a0, a1, a2, j0, j1, j2);
            ins3(sv[o*3+2], si[o*3+2], a0, a1, a2, j0, j1, j2);
            sv[tid*3] = a0; sv[tid*3+1] = a1; sv[tid*3+2] = a2;
            si[tid*3] = j0; si[tid*3+1] = j1; si[tid*3+2] = j2;
        }
        __syncthreads();
    }

    if (tid < 3) {
        int L = si[tid];
        locs3[tid] = L;
        int start, bpl;
        if (L < 1444)      { start = 4 * L;                 bpl = 4; }
        else if (L < 1805) { start = 5776 + 6 * (L - 1444); bpl = 6; }
        else if (L < 1905) { start = 7942 + 6 * (L - 1805); bpl = 6; }
        else if (L < 1930) { start = 8542 + 6 * (L - 1905); bpl = 6; }
        else if (L < 1939) { start = 8692 + 4 * (L - 1930); bpl = 4; }
        else               { start = 8728;                  bpl = 4; }
        sj_start[tid] = start; sj_bpl[tid] = bpl;
    }
    __syncthreads();
    if (tid < 10) {   // parallel candidate loads (sum bpl >= 12 -> always 10 candidates)
        const int b0 = sj_bpl[0], b1 = sj_bpl[1];
        int j, o;
        if (tid < b0)           { j = 0; o = tid; }
        else if (tid < b0 + b1) { j = 1; o = tid - b0; }
        else                    { j = 2; o = tid - b0 - b1; }
        const int p = sj_start[j] + o;
        sjj[tid]   = j;
        spres[tid] = z_present[b * NPRI + p];
        const float4 zw = *reinterpret_cast<const float4*>(z_where + (b * NPRI + p) * 4);
        szw[tid][0] = zw.x; szw[tid][1] = zw.y; szw[tid][2] = zw.z; szw[tid][3] = zw.w;
    }
    __syncthreads();
    if (tid == 0) {
        int cnt = 0;
        for (int i = 0; i < 10; ++i) {
            if (spres[i] == 1) {
                float p0 = __fadd_rn(szw[i][2], 1e-6f);
                float p1 = __fadd_rn(szw[i][3], 1e-6f);
                float p2 = __fsub_rn(__fmul_rn(2.0f, szw[i][0]), 1.0f);
                float p3 = __fsub_rn(__fmul_rn(2.0f, szw[i][1]), 1.0f);
                float* pf = paramsF + (b * KOBJ + cnt) * 4;
                pf[0] = p0; pf[1] = p1; pf[2] = p2; pf[3] = p3;
                lpf[cnt][0] = p0; lpf[cnt][1] = p1; lpf[cnt][2] = p2; lpf[cnt][3] = p3;
                paramsI[b * 12 + 2 + cnt] = b * 3 + sjj[i];
                cnt++;
            }
        }
        paramsI[b * 12] = cnt;
        lcnt = cnt;
    }
    __syncthreads();
    // exact integer coverage intervals: ty 0=xlo 1=xhi 2=ylo 3=yhi
    if (tid < 4 * KOBJ) {
        const int k = tid >> 2, ty = tid & 3;
        if (k < lcnt) {
            const float wh = (ty < 2) ? lpf[k][0] : lpf[k][1];
            const float sh = (ty < 2) ? lpf[k][2] : lpf[k][3];
            int res;
            if ((ty & 1) == 0) {           // first index with chain > -1
                int lo = 0, hi = 300;
                while (lo < hi) { int m = (lo + hi) >> 1;
                    if (ix_chain(m, sh, wh) > -1.0f) hi = m; else lo = m + 1; }
                res = lo;
            } else {                        // last index with chain < 64
                int lo = -1, hi = 299;
                while (lo < hi) { int m = (lo + hi + 1) >> 1;
                    if (ix_chain(m, sh, wh) < 64.0f) lo = m; else hi = m - 1; }
                res = lo;
            }
            obnd[(b * KOBJ + k) * 4 + ty] = res;
        }
    }
    if (tid < 192) {
        int j = tid >> 6, c = tid & 63;
        gathered[(b * 3 + j) * 64 + c] = z_what[(b * NLOC + locs3[j]) * 64 + c];
    }
}

// ---------------------------------------------------------------------------
// Fused 6-layer decoder, 48 samples, groups of 2 -> grid 16x24 = 384 blocks
// (was 192: 1 block/CU starved latency hiding). Sample-minor [c][2s] in LDS.
// ---------------------------------------------------------------------------
__global__ __launch_bounds__(256) void dec_fused(
    const float* __restrict__ gathered, const float* __restrict__ Wr,
    const float* __restrict__ b0v, const float* __restrict__ b1v,
    const float* __restrict__ W2, const float* __restrict__ b2v,
    const float* __restrict__ W3, const float* __restrict__ b3v,
    const float* __restrict__ W4, const float* __restrict__ b4v,
    const float* __restrict__ W5, const float* __restrict__ b5v,
    float* __restrict__ decoded)
{
    __shared__ __align__(16) float P[2048];
    __shared__ __align__(16) float Q[1024];
    __shared__ __align__(16) float Zs[128];
    const int r  = blockIdx.x;                // 0..15: L1-out px
    const int g  = blockIdx.y;                // 0..23: sample pair
    const int t  = threadIdx.x;
    const int y1 = r >> 2, x1 = r & 3;
    const int q0 = (y1 >> 1) * 2 + (x1 >> 1);
    const int p1 = (y1 & 1) * 2 + (x1 & 1);
    const int s2 = g * 2;

    if (t < 128) Zs[t] = gathered[(s2 + (t & 1)) * 64 + (t >> 1)];
    __syncthreads();

    // ---- L0: o = t ----
    {
        const float* w0 = Wr + q0 * 16384 + t;
        float bv = b0v[t];
        float2 acc = make_float2(bv, bv);
        #pragma unroll 8
        for (int c = 0; c < 64; ++c) {
            float w = w0[c << 8];
            float2 xs = *reinterpret_cast<const float2*>(Zs + (c << 1));
            acc.x = fmaf(xs.x, w, acc.x); acc.y = fmaf(xs.y, w, acc.y);
        }
        *reinterpret_cast<float2*>(P + (t << 1)) =
            make_float2(fmaxf(acc.x, 0.f), fmaxf(acc.y, 0.f));
    }
    __syncthreads();

    // ---- L1: o = t&127, c halved by h ----
    {
        const int o = t & 127, h = t >> 7;
        const float* w1 = Wr + 65536 + p1 * 32768 + o;
        float2 acc;
        if (h == 0) { float bv = b1v[o]; acc = make_float2(bv, bv); }
        else        { acc = make_float2(0.f, 0.f); }
        const int cb = h << 7;
        #pragma unroll 8
        for (int c = 0; c < 128; ++c) {
            float w = w1[(cb + c) << 7];
            float2 xs = *reinterpret_cast<const float2*>(P + ((cb + c) << 1));
            acc.x = fmaf(xs.x, w, acc.x); acc.y = fmaf(xs.y, w, acc.y);
        }
        if (h == 1) *reinterpret_cast<float2*>(P + 512 + (o << 1)) = acc;
        __syncthreads();
        if (h == 0) {
            float2 p2 = *reinterpret_cast<const float2*>(P + 512 + (o << 1));
            acc.x += p2.x; acc.y += p2.y;
            *reinterpret_cast<float2*>(Q + (o << 1)) =
                make_float2(fmaxf(acc.x, 0.f), fmaxf(acc.y, 0.f));
        }
    }
    __syncthreads();

    // ---- L2: f = t ----
    {
        const float* w2 = W2 + t;
        float bv = b2v[t >> 2];
        float2 acc = make_float2(bv, bv);
        #pragma unroll 8
        for (int ci = 0; ci < 128; ++ci) {
            float w = w2[ci << 8];
            float2 xs = *reinterpret_cast<const float2*>(Q + (ci << 1));
            acc.x = fmaf(xs.x, w, acc.x); acc.y = fmaf(xs.y, w, acc.y);
        }
        *reinterpret_cast<float2*>(P + (t << 1)) =
            make_float2(fmaxf(acc.x, 0.f), fmaxf(acc.y, 0.f));
    }
    __syncthreads();

    // ---- L3: px = t&15, coa = t>>4 handles {coa, coa+16} ----
    {
        const int px = t & 15, coa = t >> 4;
        const int ly = px >> 2, lx = px & 3;
        const int par = (ly >> 1) * 2 + (lx >> 1);
        const int wp  = (ly & 1) * 2 + (lx & 1);
        const float* w3 = W3 + coa * 4 + wp;
        float bva = b3v[coa], bvb = b3v[coa + 16];
        float2 a0 = make_float2(bva, bva);
        float2 a1 = make_float2(bvb, bvb);
        #pragma unroll 8
        for (int ci = 0; ci < 64; ++ci) {
            float2 xs = *reinterpret_cast<const float2*>(P + (ci << 3) + (par << 1));
            float wa = w3[ci << 7];
            float wb = w3[(ci << 7) + 64];
            a0.x = fmaf(xs.x, wa, a0.x); a0.y = fmaf(xs.y, wa, a0.y);
            a1.x = fmaf(xs.x, wb, a1.x); a1.y = fmaf(xs.y, wb, a1.y);
        }
        *reinterpret_cast<float2*>(Q + (coa << 5) + (px << 1)) =
            make_float2(fmaxf(a0.x, 0.f), fmaxf(a0.y, 0.f));
        *reinterpret_cast<float2*>(Q + ((coa + 16) << 5) + (px << 1)) =
            make_float2(fmaxf(a1.x, 0.f), fmaxf(a1.y, 0.f));
    }
    __syncthreads();

    // ---- L4: px = t&63, co = t>>6 + {0,4,8,12} ----
    {
        const int px = t & 63, co0 = t >> 6;
        const int ly = px >> 3, lx = px & 7;
        const int par = (ly >> 1) * 4 + (lx >> 1);
        const int wp  = (ly & 1) * 2 + (lx & 1);
        const float* w4 = W4 + co0 * 4 + wp;
        float2 acc[4];
        #pragma unroll
        for (int k = 0; k < 4; ++k) { float bv = b4v[co0 + 4 * k]; acc[k] = make_float2(bv, bv); }
        #pragma unroll 4
        for (int ci = 0; ci < 32; ++ci) {
            float2 xs = *reinterpret_cast<const float2*>(Q + (ci << 5) + (par << 1));
            #pragma unroll
            for (int k = 0; k < 4; ++k) {
                float w = w4[(ci << 6) + k * 16];
                acc[k].x = fmaf(xs.x, w, acc[k].x); acc[k].y = fmaf(xs.y, w, acc[k].y);
            }
        }
        #pragma unroll
        for (int k = 0; k < 4; ++k)
            *reinterpret_cast<float2*>(P + ((co0 + 4 * k) << 7) + (px << 1)) =
                make_float2(fmaxf(acc[k].x, 0.f), fmaxf(acc[k].y, 0.f));
    }
    __syncthreads();

    // ---- L5: px = t, sigmoid -> global channel-last ----
    {
        const int px = t;
        const int ly = px >> 4, lx = px & 15;
        const int par = (ly >> 1) * 8 + (lx >> 1);
        const int wp  = (ly & 1) * 2 + (lx & 1);
        const int gy = y1 * 16 + ly, gx = x1 * 16 + lx;
        const float* w5 = W5 + wp;
        float2 acc[3];
        #pragma unroll
        for (int c = 0; c < 3; ++c) { float bv = b5v[c]; acc[c] = make_float2(bv, bv); }
        #pragma unroll 4
        for (int ci = 0; ci < 16; ++ci) {
            float2 xs = *reinterpret_cast<const float2*>(P + (ci << 7) + (par << 1));
            #pragma unroll
            for (int c = 0; c < 3; ++c) {
                float w = w5[ci * 12 + c * 4];
                acc[c].x = fmaf(xs.x, w, acc[c].x); acc[c].y = fmaf(xs.y, w, acc[c].y);
            }
        }
        const int pbase = (gy * 64 + gx) * 3;
        #pragma unroll
        for (int c = 0; c < 3; ++c) {
            decoded[(s2 + 0) * 12288 + pbase + c] = 1.0f / (1.0f + expf(-acc[c].x));
            decoded[(s2 + 1) * 12288 + pbase + c] = 1.0f / (1.0f + expf(-acc[c].y));
        }
    }
}

// ---------------------------------------------------------------------------
// STN + first-nonzero composite. Coverage culling via EXACT precomputed
// integer intervals (misses = 2 int compares, no div). Geometry chain on hits
// is bitwise = reference.
// ---------------------------------------------------------------------------
__global__ __launch_bounds__(256) void stn_kernel(
    const float* __restrict__ decoded, const float* __restrict__ paramsF,
    const int* __restrict__ paramsI, const int* __restrict__ obnd,
    float* __restrict__ out)
{
    const int b = blockIdx.y;
    const int pix0 = blockIdx.x * 256;
    const int yfirst = pix0 / 300;
    __shared__ float sp[KOBJ][4];
    __shared__ int   ssamp[KOBJ];
    __shared__ int   s_xlo[KOBJ], s_xhi[KOBJ], s_ylo[KOBJ], s_yhi[KOBJ];
    __shared__ int   scnt;
    __shared__ float s_wy0[KOBJ][2], s_wy1[KOBJ][2];
    __shared__ int   s_rb0[KOBJ][2], s_rb1[KOBJ][2];
    __shared__ unsigned char s_cov[KOBJ][2];
    __shared__ unsigned char s_vy[KOBJ][2];
    __shared__ int s_list[KOBJ];
    __shared__ int s_lc;
    const int tid = threadIdx.x;

    if (tid == 0) scnt = paramsI[b * 12];
    if (tid < KOBJ) {
        #pragma unroll
        for (int c = 0; c < 4; ++c) sp[tid][c] = paramsF[(b * KOBJ + tid) * 4 + c];
        ssamp[tid] = paramsI[b * 12 + 2 + tid];
        const int4 bd = *reinterpret_cast<const int4*>(obnd + (b * KOBJ + tid) * 4);
        s_xlo[tid] = bd.x; s_xhi[tid] = bd.y; s_ylo[tid] = bd.z; s_yhi[tid] = bd.w;
    }
    __syncthreads();

    if (tid < 2 * scnt) {
        const int k = tid >> 1, sel = tid & 1;
        int yy = yfirst + sel; if (yy > 299) yy = 299;
        const bool cov = (yy >= s_ylo[k]) && (yy <= s_yhi[k]);
        s_cov[k][sel] = cov ? 1 : 0;
        if (cov) {
            const float iy = ix_chain(yy, sp[k][3], sp[k][1]);
            const float iy0f = floorf(iy);
            const float iy1f = __fadd_rn(iy0f, 1.0f);
            const float wy1  = __fsub_rn(iy, iy0f);
            s_wy1[k][sel] = wy1;
            s_wy0[k][sel] = __fsub_rn(1.0f, wy1);
            const bool vy0 = (iy0f >= 0.0f) && (iy0f < 64.0f);
            const bool vy1 = (iy1f >= 0.0f) && (iy1f < 64.0f);
            s_vy[k][sel] = (unsigned char)((vy0 ? 1 : 0) | (vy1 ? 2 : 0));
            s_rb0[k][sel] = ((int)fminf(fmaxf(iy0f, 0.0f), 63.0f)) * 64;
            s_rb1[k][sel] = ((int)fminf(fmaxf(iy1f, 0.0f), 63.0f)) * 64;
        }
    }
    __syncthreads();
    if (tid == 0) {
        int lc = 0;
        for (int k = 0; k < scnt; ++k)
            if (s_cov[k][0] | s_cov[k][1]) s_list[lc++] = k;
        s_lc = lc;
    }
    __syncthreads();

    const int pix = pix0 + tid;
    if (pix < 90000) {
        const int y = pix / 300;
        const int x = pix - y * 300;
        const int rs = y - yfirst;
        float o0 = 0.0f, o1 = 0.0f, o2 = 0.0f;
        bool d0 = false, d1 = false, d2 = false;
        const int lc = s_lc;
        for (int m = 0; m < lc; ++m) {
            const int k = s_list[m];
            if (!s_cov[k][rs]) continue;
            if (x < s_xlo[k] || x > s_xhi[k]) continue;   // exact integer coverage cull

            const float ix = ix_chain(x, sp[k][2], sp[k][0]);
            const float ix0f = floorf(ix);
            const float ix1f = __fadd_rn(ix0f, 1.0f);
            const float wx1 = __fsub_rn(ix, ix0f);
            const float wx0 = __fsub_rn(1.0f, wx1);
            const bool vx0 = (ix0f >= 0.0f) && (ix0f < 64.0f);
            const bool vx1 = (ix1f >= 0.0f) && (ix1f < 64.0f);
            const int x0 = (int)fminf(fmaxf(ix0f, 0.0f), 63.0f);
            const int x1 = (int)fminf(fmaxf(ix1f, 0.0f), 63.0f);

            const float wy0 = s_wy0[k][rs], wy1 = s_wy1[k][rs];
            const int rb0 = s_rb0[k][rs], rb1 = s_rb1[k][rs];
            const unsigned char vy = s_vy[k][rs];
            const bool m00 = (vy & 1) && vx0, m01 = (vy & 1) && vx1;
            const bool m10 = (vy & 2) && vx0, m11 = (vy & 2) && vx1;
            const float* img = decoded + ssamp[k] * 12288;

            float g00x = 0.f, g00y = 0.f, g00z = 0.f;
            float g01x = 0.f, g01y = 0.f, g01z = 0.f;
            float g10x = 0.f, g10y = 0.f, g10z = 0.f;
            float g11x = 0.f, g11y = 0.f, g11z = 0.f;
            if (m00) { const float* p = img + (rb0 + x0) * 3; g00x = p[0]; g00y = p[1]; g00z = p[2]; }
            if (m01) { const float* p = img + (rb0 + x1) * 3; g01x = p[0]; g01y = p[1]; g01z = p[2]; }
            if (m10) { const float* p = img + (rb1 + x0) * 3; g10x = p[0]; g10y = p[1]; g10z = p[2]; }
            if (m11) { const float* p = img + (rb1 + x1) * 3; g11x = p[0]; g11y = p[1]; g11z = p[2]; }

            if (!d0) {
                float val = g00x * wy0 * wx0 + g01x * wy0 * wx1 + g10x * wy1 * wx0 + g11x * wy1 * wx1;
                if (val != 0.0f) { o0 = val; d0 = true; }
            }
            if (!d1) {
                float val = g00y * wy0 * wx0 + g01y * wy0 * wx1 + g10y * wy1 * wx0 + g11y * wy1 * wx1;
                if (val != 0.0f) { o1 = val; d1 = true; }
            }
            if (!d2) {
                float val = g00z * wy0 * wx0 + g01z * wy0 * wx1 + g10z * wy1 * wx0 + g11z * wy1 * wx1;
                if (val != 0.0f) { o2 = val; d2 = true; }
            }
            if (d0 && d1 && d2) break;
        }
        const int ob = b * 270000 + pix;
        out[ob] = o0;
        out[ob + 90000] = o1;
        out[ob + 180000] = o2;
    }
}

extern "C" void kernel_launch(void* const* d_in, const int* in_sizes, int n_in,
                              void* d_out, int out_size, void* d_ws, size_t ws_size,
                              hipStream_t stream)
{
    const float* z_what    = (const float*)d_in[0];
    const float* z_where   = (const float*)d_in[1];
    const int*   z_present = (const int*)d_in[2];
    const float* z_depth   = (const float*)d_in[3];
    const float* W0 = (const float*)d_in[4];   const float* b0 = (const float*)d_in[5];
    const float* W1 = (const float*)d_in[6];   const float* b1 = (const float*)d_in[7];
    const float* W2 = (const float*)d_in[8];   const float* b2 = (const float*)d_in[9];
    const float* W3 = (const float*)d_in[10];  const float* b3 = (const float*)d_in[11];
    const float* W4 = (const float*)d_in[12];  const float* b4 = (const float*)d_in[13];
    const float* W5 = (const float*)d_in[14];  const float* b5 = (const float*)d_in[15];

    float* ws = (float*)d_ws;
    float* gathered = ws;                       // 48*64 floats
    float* paramsF  = ws + 16384;               // 640 floats
    int*   paramsI  = (int*)(ws + 17408);       // 192 ints
    int*   obnd     = (int*)(ws + 17664);       // 640 ints (16-aligned)
    float* decoded  = ws + 32768;               // 48*12288 floats, channel-last (~2.4 MB)
    float* Wr       = (float*)d_out;            // scratch until stn overwrites
    float* outp     = (float*)d_out;

    hipLaunchKernelGGL(prep_kernel, dim3(784), dim3(256), 0, stream,
                       W0, W1, Wr, z_what, z_where, z_present, z_depth,
                       gathered, paramsF, paramsI, obnd);
    hipLaunchKernelGGL(dec_fused, dim3(16, 24), dim3(256), 0, stream,
                       gathered, Wr, b0, b1, W2, b2, W3, b3, W4, b4, W5, b5, decoded);
    hipLaunchKernelGGL(stn_kernel, dim3(352, BATCH), dim3(256), 0, stream,
                       decoded, paramsF, paramsI, obnd, outp);
}